// Round 4
// baseline (391.324 us; speedup 1.0000x reference)
//
#include <hip/hip_runtime.h>
#include <math.h>

#define B_ 4
#define S_ 2048
#define H_ 768
#define NH_ 12
#define HD_ 64
#define BSH (B_ * S_ * H_)
#define NROWS (B_ * S_)
#define WSZ (H_ * H_)  // 589824

typedef __attribute__((ext_vector_type(8))) short bf16x8;
typedef __attribute__((ext_vector_type(4))) short s16x4;
typedef __attribute__((ext_vector_type(4))) float f32x4;
typedef __attribute__((ext_vector_type(2))) unsigned u32x2;
typedef __attribute__((ext_vector_type(4))) unsigned u32x4;

__device__ __forceinline__ short f2bf(float f) {
  union { float f; unsigned u; } x; x.f = f;
  unsigned r = x.u + 0x7FFF + ((x.u >> 16) & 1);
  return (short)(r >> 16);
}
__device__ __forceinline__ float bf2f(short s) {
  union { unsigned u; float f; } x;
  x.u = ((unsigned)(unsigned short)s) << 16;
  return x.f;
}
// pack 2 fp32 -> 2 bf16 (truncation) in one v_perm_b32
__device__ __forceinline__ unsigned bfpack(float lo, float hi) {
  union { float f; unsigned u; } a, b; a.f = lo; b.f = hi;
  return __builtin_amdgcn_perm(b.u, a.u, 0x07060302);
}

// permlane swaps, hardened: builtin if available, else inline asm (the
// instructions exist on gfx950 regardless of builtin availability).
__device__ __forceinline__ void plswap32(unsigned& a, unsigned& b) {
#if __has_builtin(__builtin_amdgcn_permlane32_swap)
  u32x2 r = __builtin_amdgcn_permlane32_swap(a, b, false, false);
  a = r.x; b = r.y;
#else
  asm volatile("v_permlane32_swap_b32 %0, %1" : "+v"(a), "+v"(b));
#endif
}
__device__ __forceinline__ void plswap16(unsigned& a, unsigned& b) {
#if __has_builtin(__builtin_amdgcn_permlane16_swap)
  u32x2 r = __builtin_amdgcn_permlane16_swap(a, b, false, false);
  a = r.x; b = r.y;
#else
  asm volatile("v_permlane16_swap_b32 %0, %1" : "+v"(a), "+v"(b));
#endif
}

// async global->LDS, 16B per lane; LDS dst = wave-uniform base + lane*16
typedef __attribute__((address_space(1))) const unsigned int g_u32;
typedef __attribute__((address_space(3))) unsigned int l_u32;
__device__ __forceinline__ void gload16(const void* g, void* l) {
  __builtin_amdgcn_global_load_lds((g_u32*)g, (l_u32*)l, 16, 0, 0);
}

// ---------------------------------------------------------------------------
// fp32 -> bf16 converters
// ---------------------------------------------------------------------------
__global__ __launch_bounds__(256) void cvt_x_k(const float* __restrict__ src,
                                               short* __restrict__ dst) {
  int i = (blockIdx.x * 256 + threadIdx.x) * 4;
  float4 v = *(const float4*)(src + i);
  s16x4 o = {f2bf(v.x), f2bf(v.y), f2bf(v.z), f2bf(v.w)};
  *(s16x4*)(dst + i) = o;
}

// w1 (Wq) is pre-scaled by C1 = 0.125*log2(e) so attn can exp2 scores directly
__global__ __launch_bounds__(256) void cvt6_k(const float* w0, const float* w1,
                                              const float* w2, const float* w3,
                                              const float* w4, const float* w5,
                                              short* __restrict__ dst) {
  int i = (blockIdx.x * 256 + threadIdx.x) * 4;
  int m = i / WSZ;
  int off = i - m * WSZ;
  const float* s = m == 0 ? w0 : m == 1 ? w1 : m == 2 ? w2 : m == 3 ? w3 : m == 4 ? w4 : w5;
  float sc = (m == 1) ? 0.1803368802f : 1.0f;
  float4 v = *(const float4*)(s + off);
  s16x4 o = {f2bf(v.x * sc), f2bf(v.y * sc), f2bf(v.z * sc), f2bf(v.w * sc)};
  *(s16x4*)(dst + i) = o;
}

// ---------------------------------------------------------------------------
// depthwise conv1d k=3 pad=1 over seq; vectorized x4, 192 thr (H/4=192)
// ---------------------------------------------------------------------------
__global__ __launch_bounds__(192) void dwconv_k(const float* __restrict__ prev,
                                                const float* __restrict__ w3,
                                                const float* __restrict__ bias,
                                                short* __restrict__ out) {
  int row = blockIdx.x;
  int s = row & (S_ - 1);
  int h = threadIdx.x * 4;
  size_t base = (size_t)row * H_ + h;
  float4 c = *(const float4*)(prev + base);
  float4 wa = *(const float4*)(w3 + h * 3);
  float4 wb = *(const float4*)(w3 + h * 3 + 4);
  float4 wc = *(const float4*)(w3 + h * 3 + 8);
  float4 bi = *(const float4*)(bias + h);
  float4 acc;
  acc.x = bi.x + c.x * wa.y;
  acc.y = bi.y + c.y * wb.x;
  acc.z = bi.z + c.z * wb.w;
  acc.w = bi.w + c.w * wc.z;
  if (s > 0) {
    float4 l = *(const float4*)(prev + base - H_);
    acc.x += l.x * wa.x; acc.y += l.y * wa.w; acc.z += l.z * wb.z; acc.w += l.w * wc.y;
  }
  if (s < S_ - 1) {
    float4 r = *(const float4*)(prev + base + H_);
    acc.x += r.x * wa.z; acc.y += r.y * wb.y; acc.z += r.z * wc.x; acc.w += r.w * wc.w;
  }
  s16x4 o = {f2bf(acc.x), f2bf(acc.y), f2bf(acc.z), f2bf(acc.w)};
  *(s16x4*)(out + base) = o;
}

// ---------------------------------------------------------------------------
// Grouped GEMM (QKV): 128x128 tiles, BK=64. 1D grid, XCD-swizzled so all
// blocks sharing an A row-panel land on one XCD (same L2).
// ---------------------------------------------------------------------------
struct GemmJob {
  const short* A; const short* W; const float* bias; short* C; int act; int tout;
  float bscale;
};

__global__ __launch_bounds__(256) void gemm_bf2(GemmJob j0, GemmJob j1, GemmJob j2) {
  int d = blockIdx.x;
  int z = d / 384, r5 = d - z * 384;
  GemmJob j = z == 0 ? j0 : (z == 1 ? j1 : j2);
  int xcd = r5 & 7, s5 = r5 >> 3;          // s5 in [0,48)
  int nx = s5 % 6, ny = xcd + 8 * (s5 / 6);  // ny in [0,64)
  __shared__ short As[128 * 64];  // 16 KB
  __shared__ short Ws[128 * 64];
  int tid = threadIdx.x, lane = tid & 63, w = tid >> 6;
  int wr = w >> 1, wc = w & 1, lm = lane & 15, lq = lane >> 4;
  int m0 = ny * 128, n0 = nx * 128;
  int srow = lane >> 3;
  int skc = (lane & 7) * 8;
  const short* gA = j.A + (size_t)(m0 + w * 32 + srow) * H_ + skc;
  const short* gW = j.W + (size_t)(n0 + w * 32 + srow) * H_ + skc;
  short* lA = As + w * 2048;
  short* lW = Ws + w * 2048;

  f32x4 acc[4][4];
#pragma unroll
  for (int i = 0; i < 4; ++i)
#pragma unroll
    for (int jj = 0; jj < 4; ++jj) acc[i][jj] = (f32x4){0.f, 0.f, 0.f, 0.f};

  for (int kt = 0; kt < H_; kt += 64) {
    __syncthreads();
#pragma unroll
    for (int c = 0; c < 4; ++c) {
      gload16(gA + kt + (size_t)(c * 8) * H_, lA + c * 512);
      gload16(gW + kt + (size_t)(c * 8) * H_, lW + c * 512);
    }
    __syncthreads();
#pragma unroll
    for (int kk = 0; kk < 2; ++kk) {
      bf16x8 af[4], wf[4];
#pragma unroll
      for (int i = 0; i < 4; ++i)
        af[i] = *(const bf16x8*)&As[(wr * 64 + i * 16 + lm) * 64 + kk * 32 + lq * 8];
#pragma unroll
      for (int jj = 0; jj < 4; ++jj)
        wf[jj] = *(const bf16x8*)&Ws[(wc * 64 + jj * 16 + lm) * 64 + kk * 32 + lq * 8];
#pragma unroll
      for (int i = 0; i < 4; ++i)
#pragma unroll
        for (int jj = 0; jj < 4; ++jj)
          acc[i][jj] = __builtin_amdgcn_mfma_f32_16x16x32_bf16(af[i], wf[jj], acc[i][jj], 0, 0, 0);
    }
  }

  if (!j.tout) {
#pragma unroll
    for (int jj = 0; jj < 4; ++jj) {
      int col = n0 + wc * 64 + jj * 16 + lm;
      float bn = j.bias[col] * j.bscale;
#pragma unroll
      for (int i = 0; i < 4; ++i) {
        int mrow = m0 + wr * 64 + i * 16 + lq * 4;
#pragma unroll
        for (int r = 0; r < 4; ++r) {
          float cv = acc[i][jj][r] + bn;
          if (j.act) cv = 0.5f * cv * (1.0f + erff(cv * 0.70710678118f));
          j.C[(size_t)(mrow + r) * H_ + col] = f2bf(cv);
        }
      }
    }
  } else {
    int b = m0 >> 11;
    int sb = (m0 & (S_ - 1)) + wr * 64;
#pragma unroll
    for (int jj = 0; jj < 4; ++jj) {
      int col = n0 + wc * 64 + jj * 16 + lm;
      float bn = j.bias[col] * j.bscale;
      short* cp = j.C + ((size_t)(b * H_ + col)) * S_;
#pragma unroll
      for (int i = 0; i < 4; ++i) {
        int s = sb + i * 16 + lq * 4;
        s16x4 pk = {f2bf(acc[i][jj][0] + bn), f2bf(acc[i][jj][1] + bn),
                    f2bf(acc[i][jj][2] + bn), f2bf(acc[i][jj][3] + bn)};
        *(s16x4*)(cp + s) = pk;
      }
    }
  }
}

// ---------------------------------------------------------------------------
// Single GEMM, 128x64 tile (768 blocks = 3.0/CU): pw/o/post projections.
// 1D grid, XCD-swizzled (A row-panel locality).
// ---------------------------------------------------------------------------
__global__ __launch_bounds__(256) void gemm_n64(const short* __restrict__ A,
                                                const short* __restrict__ W,
                                                const float* __restrict__ bias,
                                                short* __restrict__ C, int act) {
  int d = blockIdx.x;
  int xcd = d & 7, s5 = d >> 3;            // s5 in [0,96)
  int nx = s5 % 12, ny = xcd + 8 * (s5 / 12);  // ny in [0,64)
  __shared__ short As[128 * 64];  // 16 KB
  __shared__ short Ws[64 * 64];   // 8 KB
  int tid = threadIdx.x, lane = tid & 63, w = tid >> 6;
  int wm = w >> 1, wn = w & 1, lm = lane & 15, lq = lane >> 4;
  int m0 = ny * 128, n0 = nx * 64;
  const short* gA = A + (size_t)(m0 + w * 32 + (lane >> 3)) * H_ + (lane & 7) * 8;
  const short* gW = W + (size_t)(n0 + w * 16 + (lane >> 3)) * H_ + (lane & 7) * 8;
  short* lA = As + w * 2048;  // 32 rows x 64
  short* lW = Ws + w * 1024;  // 16 rows x 64

  f32x4 acc[4][2];
#pragma unroll
  for (int i = 0; i < 4; ++i)
#pragma unroll
    for (int jj = 0; jj < 2; ++jj) acc[i][jj] = (f32x4){0.f, 0.f, 0.f, 0.f};

  for (int kt = 0; kt < H_; kt += 64) {
    __syncthreads();
#pragma unroll
    for (int c = 0; c < 4; ++c)
      gload16(gA + kt + (size_t)(c * 8) * H_, lA + c * 512);
#pragma unroll
    for (int c = 0; c < 2; ++c)
      gload16(gW + kt + (size_t)(c * 8) * H_, lW + c * 512);
    __syncthreads();
#pragma unroll
    for (int kk = 0; kk < 2; ++kk) {
      bf16x8 af[4], wf[2];
#pragma unroll
      for (int i = 0; i < 4; ++i)
        af[i] = *(const bf16x8*)&As[(wm * 64 + i * 16 + lm) * 64 + kk * 32 + lq * 8];
#pragma unroll
      for (int jj = 0; jj < 2; ++jj)
        wf[jj] = *(const bf16x8*)&Ws[(wn * 32 + jj * 16 + lm) * 64 + kk * 32 + lq * 8];
#pragma unroll
      for (int i = 0; i < 4; ++i)
#pragma unroll
        for (int jj = 0; jj < 2; ++jj)
          acc[i][jj] = __builtin_amdgcn_mfma_f32_16x16x32_bf16(af[i], wf[jj], acc[i][jj], 0, 0, 0);
    }
  }

#pragma unroll
  for (int jj = 0; jj < 2; ++jj) {
    int col = n0 + wn * 32 + jj * 16 + lm;
    float bn = bias[col];
#pragma unroll
    for (int i = 0; i < 4; ++i) {
      int mrow = m0 + wm * 64 + i * 16 + lq * 4;
#pragma unroll
      for (int r = 0; r < 4; ++r) {
        float cv = acc[i][jj][r] + bn;
        if (act) cv = 0.5f * cv * (1.0f + erff(cv * 0.70710678118f));
        C[(size_t)(mrow + r) * H_ + col] = f2bf(cv);
      }
    }
  }
}

// ---------------------------------------------------------------------------
// LayerNorm over last dim (H=768), bf16 in -> bf16 out
// ---------------------------------------------------------------------------
__global__ __launch_bounds__(256) void ln_bf(const short* __restrict__ X,
                                             short* __restrict__ Y,
                                             const float* __restrict__ g,
                                             const float* __restrict__ bb) {
  int row = blockIdx.x;
  size_t base = (size_t)row * H_;
  int h0 = threadIdx.x, h1 = h0 + 256, h2 = h0 + 512;
  float x0 = bf2f(X[base + h0]), x1 = bf2f(X[base + h1]), x2 = bf2f(X[base + h2]);
  float s = x0 + x1 + x2;
  float s2 = x0 * x0 + x1 * x1 + x2 * x2;
  for (int off = 32; off > 0; off >>= 1) {
    s += __shfl_down(s, off);
    s2 += __shfl_down(s2, off);
  }
  __shared__ float sa[4], sq[4], st[2];
  int wid = threadIdx.x >> 6, lane = threadIdx.x & 63;
  if (lane == 0) { sa[wid] = s; sq[wid] = s2; }
  __syncthreads();
  if (threadIdx.x == 0) {
    float ts = sa[0] + sa[1] + sa[2] + sa[3];
    float ts2 = sq[0] + sq[1] + sq[2] + sq[3];
    float mean = ts * (1.0f / H_);
    float var = ts2 * (1.0f / H_) - mean * mean;
    st[0] = mean;
    st[1] = rsqrtf(var + 1e-5f);
  }
  __syncthreads();
  float mean = st[0], rstd = st[1];
  Y[base + h0] = f2bf((x0 - mean) * rstd * g[h0] + bb[h0]);
  Y[base + h1] = f2bf((x1 - mean) * rstd * g[h1] + bb[h1]);
  Y[base + h2] = f2bf((x2 - mean) * rstd * g[h2] + bb[h2]);
}

// ---------------------------------------------------------------------------
// MFMA flash attention v7. Changes vs v6:
//  - P never touches LDS: the C-layout -> B-operand-layout exchange (lanes
//    {lm, lm+16, lm+32, lm+48} only) is done in-register with
//    permlane32_swap + permlane16_swap (2 per packed word-pair).
//    Removes 8 ds_write_b64 + 4 ds_read_b128 + lgkmcnt waits per wave-tile;
//    Ps buffer (16 KB) deleted -> LDS 32 KB.
//  - s_setprio(1) around MFMA clusters (T5).
// ---------------------------------------------------------------------------
__global__ __launch_bounds__(256) void attn7_k(const short* __restrict__ qb,
                                               const short* __restrict__ kb,
                                               const short* __restrict__ vtb,
                                               short* __restrict__ aob) {
  __shared__ short Ks[2][64 * 64];     // [sk][d] swizzled, 2 x 8 KB
  __shared__ short Vt[2][64 * 64];     // [d][sk] swizzled, 2 x 8 KB
  int tid = threadIdx.x, lane = tid & 63, w = tid >> 6;  // w 0..3
  int lm = lane & 15, lq = lane >> 4;
  int lm7 = lm & 7;
  // XCD-swizzled decode: g=(b,n) group, all 16 q-blocks of g on one XCD
  int dd = blockIdx.x;
  int xcd = dd & 7, slot = dd >> 3;          // slot in [0,96)
  int g = xcd + 8 * (slot >> 4);             // g in [0,48)
  int qx = slot & 15;
  int b = g / NH_, n = g - b * NH_;
  int q0 = qx * 128;
  int hoff = n * HD_;

  // swizzled fragment slot offsets (in shorts): logical 16B-slot lq / lq+4
  int rb8 = (lq ^ lm7) << 3;
  int rb8x = rb8 ^ 32;

  bf16x8 qf[2][2];
#pragma unroll
  for (int qg = 0; qg < 2; ++qg) {
    const short* qrow = qb + ((size_t)(b * S_ + q0 + w * 32 + qg * 16 + lm)) * H_ + hoff;
    qf[qg][0] = *(const bf16x8*)(qrow + lq * 8);
    qf[qg][1] = *(const bf16x8*)(qrow + 32 + lq * 8);
  }

  // ones A-fragment (bf16 1.0) for MFMA row-sum of P
  bf16x8 onef = {0x3F80, 0x3F80, 0x3F80, 0x3F80, 0x3F80, 0x3F80, 0x3F80, 0x3F80};
  f32x4 ls[2];
  ls[0] = (f32x4){0.f, 0.f, 0.f, 0.f};
  ls[1] = (f32x4){0.f, 0.f, 0.f, 0.f};

  f32x4 o[4][2];
#pragma unroll
  for (int i = 0; i < 4; ++i)
#pragma unroll
    for (int qg = 0; qg < 2; ++qg) o[i][qg] = (f32x4){0.f, 0.f, 0.f, 0.f};

  // staging: row = tid>>2 (0..63), 2x16B each of K,V at logical slots 2j, 2j+1
  int r0 = tid >> 2;
  int c0 = (tid & 3) * 16;
  int sl = (tid & 3) * 2;
  int sw0 = r0 * 64 + ((sl ^ (r0 & 7)) << 3);
  int sw1 = r0 * 64 + (((sl ^ 1) ^ (r0 & 7)) << 3);
  const short* kg = kb + ((size_t)(b * S_)) * H_ + hoff;
  const short* vg = vtb + ((size_t)(b * H_ + hoff)) * S_;

  bf16x8 kv0 = *(const bf16x8*)(kg + (size_t)r0 * H_ + c0);
  bf16x8 kv1 = *(const bf16x8*)(kg + (size_t)r0 * H_ + c0 + 8);
  bf16x8 vv0 = *(const bf16x8*)(vg + (size_t)r0 * S_ + c0);
  bf16x8 vv1 = *(const bf16x8*)(vg + (size_t)r0 * S_ + c0 + 8);

  for (int kt = 0, pb = 0; kt < S_; kt += 64, pb ^= 1) {
    short* Kw = &Ks[pb][0];
    short* Vw = &Vt[pb][0];
    // write this tile's staged regs into buf[pb]; previous iter's readers are
    // on buf[pb^1], so no pre-write barrier needed.
    *(bf16x8*)&Kw[sw0] = kv0;
    *(bf16x8*)&Kw[sw1] = kv1;
    *(bf16x8*)&Vw[sw0] = vv0;
    *(bf16x8*)&Vw[sw1] = vv1;
    __syncthreads();
    if (kt + 64 < S_) {
      kv0 = *(const bf16x8*)(kg + (size_t)(kt + 64 + r0) * H_ + c0);
      kv1 = *(const bf16x8*)(kg + (size_t)(kt + 64 + r0) * H_ + c0 + 8);
      vv0 = *(const bf16x8*)(vg + (size_t)r0 * S_ + kt + 64 + c0);
      vv1 = *(const bf16x8*)(vg + (size_t)r0 * S_ + kt + 64 + c0 + 8);
    }

    // ---- S^T[sk][q]: sk = ni*16 + lq*4 + r, q = lm (per q-group) ----
    f32x4 st[4][2];
    __builtin_amdgcn_s_setprio(1);
#pragma unroll
    for (int ni = 0; ni < 4; ++ni) {
      int krow = (ni * 16 + lm) * 64;
      bf16x8 ka0 = *(const bf16x8*)&Kw[krow + rb8];
      bf16x8 ka1 = *(const bf16x8*)&Kw[krow + rb8x];
#pragma unroll
      for (int qg = 0; qg < 2; ++qg) {
        f32x4 z = (f32x4){0.f, 0.f, 0.f, 0.f};
        z = __builtin_amdgcn_mfma_f32_16x16x32_bf16(ka0, qf[qg][0], z, 0, 0, 0);
        st[ni][qg] = __builtin_amdgcn_mfma_f32_16x16x32_bf16(ka1, qf[qg][1], z, 0, 0, 0);
      }
    }
    __builtin_amdgcn_s_setprio(0);

    // ---- exp (scores pre-scaled) + pack + in-register B-layout xform ----
    // producer: word (ni, half) = pack(P[sk=16ni+4lq+{0,1}]), pack(+{2,3})
    // consumer B-word j-pair for chunk c: built via pl32+pl16 swaps among
    // lanes {lm, lm+16, lm+32, lm+48}.
    bf16x8 pf[2][2];
#pragma unroll
    for (int qg = 0; qg < 2; ++qg) {
      unsigned pw0, pw1, pw2, pw3, pw4, pw5, pw6, pw7;
      {
        float p0 = exp2f(st[0][qg][0]), p1 = exp2f(st[0][qg][1]);
        float p2 = exp2f(st[0][qg][2]), p3 = exp2f(st[0][qg][3]);
        pw0 = bfpack(p0, p1); pw1 = bfpack(p2, p3);
      }
      {
        float p0 = exp2f(st[1][qg][0]), p1 = exp2f(st[1][qg][1]);
        float p2 = exp2f(st[1][qg][2]), p3 = exp2f(st[1][qg][3]);
        pw2 = bfpack(p0, p1); pw3 = bfpack(p2, p3);
      }
      {
        float p0 = exp2f(st[2][qg][0]), p1 = exp2f(st[2][qg][1]);
        float p2 = exp2f(st[2][qg][2]), p3 = exp2f(st[2][qg][3]);
        pw4 = bfpack(p0, p1); pw5 = bfpack(p2, p3);
      }
      {
        float p0 = exp2f(st[3][qg][0]), p1 = exp2f(st[3][qg][1]);
        float p2 = exp2f(st[3][qg][2]), p3 = exp2f(st[3][qg][3]);
        pw6 = bfpack(p0, p1); pw7 = bfpack(p2, p3);
      }
      // chunk 0 (sk 0..31): ni 0,1  -> words j0..j3 across lq groups
      plswap32(pw0, pw2); plswap16(pw0, pw2);   // pw0=j0, pw2=j2
      plswap32(pw1, pw3); plswap16(pw1, pw3);   // pw1=j1, pw3=j3
      // chunk 1 (sk 32..63): ni 2,3
      plswap32(pw4, pw6); plswap16(pw4, pw6);   // pw4=j0, pw6=j2
      plswap32(pw5, pw7); plswap16(pw5, pw7);   // pw5=j1, pw7=j3
      union { u32x4 u; bf16x8 v; } c0u, c1u;
      c0u.u = (u32x4){pw0, pw1, pw2, pw3};
      c1u.u = (u32x4){pw4, pw5, pw6, pw7};
      pf[qg][0] = c0u.v;
      pf[qg][1] = c1u.v;
    }

    // ---- O^T += V^T P^T ; denominator += 1^T P^T (matrix pipe) ----
    __builtin_amdgcn_s_setprio(1);
#pragma unroll
    for (int qg = 0; qg < 2; ++qg) {
      ls[qg] = __builtin_amdgcn_mfma_f32_16x16x32_bf16(onef, pf[qg][0], ls[qg], 0, 0, 0);
      ls[qg] = __builtin_amdgcn_mfma_f32_16x16x32_bf16(onef, pf[qg][1], ls[qg], 0, 0, 0);
    }
#pragma unroll
    for (int nd = 0; nd < 4; ++nd) {
      int vrow = (nd * 16 + lm) * 64;
      bf16x8 va0 = *(const bf16x8*)&Vw[vrow + rb8];
      bf16x8 va1 = *(const bf16x8*)&Vw[vrow + rb8x];
#pragma unroll
      for (int qg = 0; qg < 2; ++qg) {
        o[nd][qg] = __builtin_amdgcn_mfma_f32_16x16x32_bf16(va0, pf[qg][0], o[nd][qg], 0, 0, 0);
        o[nd][qg] = __builtin_amdgcn_mfma_f32_16x16x32_bf16(va1, pf[qg][1], o[nd][qg], 0, 0, 0);
      }
    }
    __builtin_amdgcn_s_setprio(0);
  }

  // epilogue: q row = q0 + w*32 + qg*16 + lm; d = nd*16 + lq*4 + r
#pragma unroll
  for (int qg = 0; qg < 2; ++qg) {
    float inv = 1.0f / ls[qg][0];
    short* orow = aob + ((size_t)(b * S_ + q0 + w * 32 + qg * 16 + lm)) * H_ + hoff;
#pragma unroll
    for (int nd = 0; nd < 4; ++nd) {
      s16x4 pk = {f2bf(o[nd][qg][0] * inv), f2bf(o[nd][qg][1] * inv),
                  f2bf(o[nd][qg][2] * inv), f2bf(o[nd][qg][3] * inv)};
      *(s16x4*)(orow + nd * 16 + lq * 4) = pk;
    }
  }
}

// ---------------------------------------------------------------------------
// gate + masked residual + aux partials. 192 thr, x4 vectorized.
// ---------------------------------------------------------------------------
__global__ __launch_bounds__(192) void gate_out_k(const float* __restrict__ x,
                                                  const short* __restrict__ br,
                                                  const short* __restrict__ inj,
                                                  const int* __restrict__ mask,
                                                  const float* __restrict__ Wg,
                                                  const float* __restrict__ bg,
                                                  float* __restrict__ out,
                                                  float* __restrict__ paux) {
  int row = blockIdx.x;
  int b = row >> 11;
  size_t base = (size_t)row * H_;
  int h = threadIdx.x * 4;
  float4 xv = *(const float4*)(x + base + h);
  s16x4 brv = *(const s16x4*)(br + base + h);
  s16x4 inv = *(const s16x4*)(inj + base + h);
  float4 wg0 = *(const float4*)(Wg + h);
  float4 wg1 = *(const float4*)(Wg + H_ + h);
  float b0 = bf2f(brv.x), b1 = bf2f(brv.y), b2 = bf2f(brv.z), b3 = bf2f(brv.w);
  float dot = xv.x * wg0.x + xv.y * wg0.y + xv.z * wg0.z + xv.w * wg0.w
            + b0 * wg1.x + b1 * wg1.y + b2 * wg1.z + b3 * wg1.w;
  float d0 = b0 - xv.x, d1 = b1 - xv.y, d2 = b2 - xv.z, d3 = b3 - xv.w;
  float aux = d0 * d0 + d1 * d1 + d2 * d2 + d3 * d3;
  for (int off = 32; off > 0; off >>= 1) {
    dot += __shfl_down(dot, off);
    aux += __shfl_down(aux, off);
  }
  __shared__ float sd[3], sx[3], gsh[2];
  int wid = threadIdx.x >> 6, lane = threadIdx.x & 63;
  if (lane == 0) { sd[wid] = dot; sx[wid] = aux; }
  __syncthreads();
  if (threadIdx.x == 0) {
    float td = sd[0] + sd[1] + sd[2];
    float ta = sx[0] + sx[1] + sx[2];
    gsh[0] = 1.0f / (1.0f + expf(-(td + bg[0])));
    gsh[1] = ta;
  }
  __syncthreads();
  float mf = (mask[b] != 0) ? 1.0f : 0.0f;
  float gm = gsh[0] * mf;
  float v0 = bf2f(inv.x), v1 = bf2f(inv.y), v2 = bf2f(inv.z), v3 = bf2f(inv.w);
  float e0 = __expf(2.f * v0), e1 = __expf(2.f * v1), e2 = __expf(2.f * v2), e3 = __expf(2.f * v3);
  float4 ov;
  ov.x = xv.x + gm * ((e0 - 1.f) / (e0 + 1.f));
  ov.y = xv.y + gm * ((e1 - 1.f) / (e1 + 1.f));
  ov.z = xv.z + gm * ((e2 - 1.f) / (e2 + 1.f));
  ov.w = xv.w + gm * ((e3 - 1.f) / (e3 + 1.f));
  *(float4*)(out + base + h) = ov;
  if (threadIdx.x == 0) paux[row] = mf * gsh[1];
}

__global__ __launch_bounds__(256) void aux_reduce_k(const float* __restrict__ paux,
                                                    const int* __restrict__ mask,
                                                    float* __restrict__ outp) {
  float s = 0.f;
  for (int i = threadIdx.x; i < NROWS; i += 256) s += paux[i];
  for (int off = 32; off > 0; off >>= 1) s += __shfl_down(s, off);
  __shared__ float sw[4];
  int wid = threadIdx.x >> 6, lane = threadIdx.x & 63;
  if (lane == 0) sw[wid] = s;
  __syncthreads();
  if (threadIdx.x == 0) {
    float t = sw[0] + sw[1] + sw[2] + sw[3];
    int nm = (mask[0] != 0) + (mask[1] != 0) + (mask[2] != 0) + (mask[3] != 0);
    if (nm < 1) nm = 1;
    outp[0] = t / ((float)nm * (float)(S_ * H_));
  }
}

// ---------------------------------------------------------------------------
extern "C" void kernel_launch(void* const* d_in, const int* in_sizes, int n_in,
                              void* d_out, int out_size, void* d_ws, size_t ws_size,
                              hipStream_t stream) {
  const float* x     = (const float*)d_in[0];
  const float* prev  = (const float*)d_in[1];
  const int*   mask  = (const int*)d_in[2];
  const float* dw_w  = (const float*)d_in[3];
  const float* dw_b  = (const float*)d_in[4];
  const float* pw_w  = (const float*)d_in[5];
  const float* pw_b  = (const float*)d_in[6];
  const float* cn_g  = (const float*)d_in[7];
  const float* cn_b  = (const float*)d_in[8];
  const float* Wq    = (const float*)d_in[9];
  const float* bq    = (const float*)d_in[10];
  const float* Wk    = (const float*)d_in[11];
  const float* bk    = (const float*)d_in[12];
  const float* Wv    = (const float*)d_in[13];
  const float* bv    = (const float*)d_in[14];
  const float* Wo    = (const float*)d_in[15];
  const float* bo    = (const float*)d_in[16];
  const float* pn_g  = (const float*)d_in[17];
  const float* pn_b  = (const float*)d_in[18];
  const float* Wpost = (const float*)d_in[19];
  const float* bpost = (const float*)d_in[20];
  const float* Wg    = (const float*)d_in[21];
  const float* bg    = (const float*)d_in[22];
  float* out = (float*)d_out;

  short* B0 = (short*)d_ws;     // xb
  short* B1 = B0 + BSH;         // dwo -> qb
  short* B2 = B1 + BSH;         // gelu-out -> aob
  short* B3 = B2 + BSH;         // bridged (until gate)
  short* B4 = B3 + BSH;         // kb -> ao_proj -> pn
  short* B5 = B4 + BSH;         // vtb -> injb
  short* WW = B5 + BSH;         // 6 bf16 weights [pw,q,k,v,o,post]
  float* paux = (float*)(WW + 6 * WSZ);

  const float C1 = 0.1803368802f;  // 0.125 * log2(e), folded into Wq/bq

  GemmJob jq = {B0, WW + WSZ,     bq, B1, 0, 0, C1};
  GemmJob jk = {B3, WW + 2 * WSZ, bk, B4, 0, 0, 1.0f};
  GemmJob jv = {B3, WW + 3 * WSZ, bv, B5, 0, 1, 1.0f};

  cvt6_k<<<6 * WSZ / 1024, 256, 0, stream>>>(pw_w, Wq, Wk, Wv, Wo, Wpost, WW);
  cvt_x_k<<<BSH / 1024, 256, 0, stream>>>(x, B0);
  dwconv_k<<<NROWS, 192, 0, stream>>>(prev, dw_w, dw_b, B1);
  gemm_n64<<<768, 256, 0, stream>>>(B1, WW, pw_b, B2, 1);                  // pw + GELU
  ln_bf<<<NROWS, 256, 0, stream>>>(B2, B3, cn_g, cn_b);                    // bridged
  gemm_bf2<<<1152, 256, 0, stream>>>(jq, jk, jv);                          // Q,K,V grouped
  attn7_k<<<768, 256, 0, stream>>>(B1, B4, B5, B2);                        // -> aob
  gemm_n64<<<768, 256, 0, stream>>>(B2, WW + 4 * WSZ, bo, B4, 0);          // o-proj
  ln_bf<<<NROWS, 256, 0, stream>>>(B4, B4, pn_g, pn_b);                    // pn
  gemm_n64<<<768, 256, 0, stream>>>(B4, WW + 5 * WSZ, bpost, B5, 0);       // post
  gate_out_k<<<NROWS, 192, 0, stream>>>(x, B3, B5, mask, Wg, bg, out, paux);
  aux_reduce_k<<<1, 256, 0, stream>>>(paux, mask, out + BSH);
}

// Round 5
// 372.252 us; speedup vs baseline: 1.0512x; 1.0512x over previous
//
#include <hip/hip_runtime.h>
#include <math.h>

#define B_ 4
#define S_ 2048
#define H_ 768
#define NH_ 12
#define HD_ 64
#define BSH (B_ * S_ * H_)
#define NROWS (B_ * S_)
#define WSZ (H_ * H_)  // 589824

typedef __attribute__((ext_vector_type(8))) short bf16x8;
typedef __attribute__((ext_vector_type(4))) short s16x4;
typedef __attribute__((ext_vector_type(4))) float f32x4;
typedef __attribute__((ext_vector_type(2))) unsigned u32x2;
typedef __attribute__((ext_vector_type(4))) unsigned u32x4;

__device__ __forceinline__ short f2bf(float f) {
  union { float f; unsigned u; } x; x.f = f;
  unsigned r = x.u + 0x7FFF + ((x.u >> 16) & 1);
  return (short)(r >> 16);
}
__device__ __forceinline__ float bf2f(short s) {
  union { unsigned u; float f; } x;
  x.u = ((unsigned)(unsigned short)s) << 16;
  return x.f;
}
// pack 2 fp32 -> 2 bf16 (truncation) in one v_perm_b32
__device__ __forceinline__ unsigned bfpack(float lo, float hi) {
  union { float f; unsigned u; } a, b; a.f = lo; b.f = hi;
  return __builtin_amdgcn_perm(b.u, a.u, 0x07060302);
}

// raw v_exp_f32 (scores are range-bounded; skip ocml denormal guards)
__device__ __forceinline__ float fexp2(float x) {
#if __has_builtin(__builtin_amdgcn_exp2f)
  return __builtin_amdgcn_exp2f(x);
#else
  float r;
  asm("v_exp_f32 %0, %1" : "=v"(r) : "v"(x));
  return r;
#endif
}

// permlane swaps, hardened: builtin if available, else inline asm
__device__ __forceinline__ void plswap32(unsigned& a, unsigned& b) {
#if __has_builtin(__builtin_amdgcn_permlane32_swap)
  u32x2 r = __builtin_amdgcn_permlane32_swap(a, b, false, false);
  a = r.x; b = r.y;
#else
  asm volatile("v_permlane32_swap_b32 %0, %1" : "+v"(a), "+v"(b));
#endif
}
__device__ __forceinline__ void plswap16(unsigned& a, unsigned& b) {
#if __has_builtin(__builtin_amdgcn_permlane16_swap)
  u32x2 r = __builtin_amdgcn_permlane16_swap(a, b, false, false);
  a = r.x; b = r.y;
#else
  asm volatile("v_permlane16_swap_b32 %0, %1" : "+v"(a), "+v"(b));
#endif
}

// async global->LDS, 16B per lane; LDS dst = wave-uniform base + lane*16
typedef __attribute__((address_space(1))) const unsigned int g_u32;
typedef __attribute__((address_space(3))) unsigned int l_u32;
__device__ __forceinline__ void gload16(const void* g, void* l) {
  __builtin_amdgcn_global_load_lds((g_u32*)g, (l_u32*)l, 16, 0, 0);
}

// ---------------------------------------------------------------------------
// fp32 -> bf16 converters
// ---------------------------------------------------------------------------
__global__ __launch_bounds__(256) void cvt_x_k(const float* __restrict__ src,
                                               short* __restrict__ dst) {
  int i = (blockIdx.x * 256 + threadIdx.x) * 4;
  float4 v = *(const float4*)(src + i);
  s16x4 o = {f2bf(v.x), f2bf(v.y), f2bf(v.z), f2bf(v.w)};
  *(s16x4*)(dst + i) = o;
}

// w1 (Wq) is pre-scaled by C1 = 0.125*log2(e) so attn can exp2 scores directly
__global__ __launch_bounds__(256) void cvt6_k(const float* w0, const float* w1,
                                              const float* w2, const float* w3,
                                              const float* w4, const float* w5,
                                              short* __restrict__ dst) {
  int i = (blockIdx.x * 256 + threadIdx.x) * 4;
  int m = i / WSZ;
  int off = i - m * WSZ;
  const float* s = m == 0 ? w0 : m == 1 ? w1 : m == 2 ? w2 : m == 3 ? w3 : m == 4 ? w4 : w5;
  float sc = (m == 1) ? 0.1803368802f : 1.0f;
  float4 v = *(const float4*)(s + off);
  s16x4 o = {f2bf(v.x * sc), f2bf(v.y * sc), f2bf(v.z * sc), f2bf(v.w * sc)};
  *(s16x4*)(dst + i) = o;
}

// ---------------------------------------------------------------------------
// depthwise conv1d k=3 pad=1 over seq; vectorized x4, 192 thr (H/4=192)
// ---------------------------------------------------------------------------
__global__ __launch_bounds__(192) void dwconv_k(const float* __restrict__ prev,
                                                const float* __restrict__ w3,
                                                const float* __restrict__ bias,
                                                short* __restrict__ out) {
  int row = blockIdx.x;
  int s = row & (S_ - 1);
  int h = threadIdx.x * 4;
  size_t base = (size_t)row * H_ + h;
  float4 c = *(const float4*)(prev + base);
  float4 wa = *(const float4*)(w3 + h * 3);
  float4 wb = *(const float4*)(w3 + h * 3 + 4);
  float4 wc = *(const float4*)(w3 + h * 3 + 8);
  float4 bi = *(const float4*)(bias + h);
  float4 acc;
  acc.x = bi.x + c.x * wa.y;
  acc.y = bi.y + c.y * wb.x;
  acc.z = bi.z + c.z * wb.w;
  acc.w = bi.w + c.w * wc.z;
  if (s > 0) {
    float4 l = *(const float4*)(prev + base - H_);
    acc.x += l.x * wa.x; acc.y += l.y * wa.w; acc.z += l.z * wb.z; acc.w += l.w * wc.y;
  }
  if (s < S_ - 1) {
    float4 r = *(const float4*)(prev + base + H_);
    acc.x += r.x * wa.z; acc.y += r.y * wb.y; acc.z += r.z * wc.x; acc.w += r.w * wc.w;
  }
  s16x4 o = {f2bf(acc.x), f2bf(acc.y), f2bf(acc.z), f2bf(acc.w)};
  *(s16x4*)(out + base) = o;
}

// ---------------------------------------------------------------------------
// Grouped GEMM (QKV): 128x128 tiles, BK=64. 1D grid, XCD-swizzled so all
// blocks sharing an A row-panel land on one XCD (same L2).
// ---------------------------------------------------------------------------
struct GemmJob {
  const short* A; const short* W; const float* bias; short* C; int act; int tout;
  float bscale;
};

__global__ __launch_bounds__(256) void gemm_bf2(GemmJob j0, GemmJob j1, GemmJob j2) {
  int d = blockIdx.x;
  int z = d / 384, r5 = d - z * 384;
  GemmJob j = z == 0 ? j0 : (z == 1 ? j1 : j2);
  int xcd = r5 & 7, s5 = r5 >> 3;          // s5 in [0,48)
  int nx = s5 % 6, ny = xcd + 8 * (s5 / 6);  // ny in [0,64)
  __shared__ short As[128 * 64];  // 16 KB
  __shared__ short Ws[128 * 64];
  int tid = threadIdx.x, lane = tid & 63, w = tid >> 6;
  int wr = w >> 1, wc = w & 1, lm = lane & 15, lq = lane >> 4;
  int m0 = ny * 128, n0 = nx * 128;
  int srow = lane >> 3;
  int skc = (lane & 7) * 8;
  const short* gA = j.A + (size_t)(m0 + w * 32 + srow) * H_ + skc;
  const short* gW = j.W + (size_t)(n0 + w * 32 + srow) * H_ + skc;
  short* lA = As + w * 2048;
  short* lW = Ws + w * 2048;

  f32x4 acc[4][4];
#pragma unroll
  for (int i = 0; i < 4; ++i)
#pragma unroll
    for (int jj = 0; jj < 4; ++jj) acc[i][jj] = (f32x4){0.f, 0.f, 0.f, 0.f};

  for (int kt = 0; kt < H_; kt += 64) {
    __syncthreads();
#pragma unroll
    for (int c = 0; c < 4; ++c) {
      gload16(gA + kt + (size_t)(c * 8) * H_, lA + c * 512);
      gload16(gW + kt + (size_t)(c * 8) * H_, lW + c * 512);
    }
    __syncthreads();
#pragma unroll
    for (int kk = 0; kk < 2; ++kk) {
      bf16x8 af[4], wf[4];
#pragma unroll
      for (int i = 0; i < 4; ++i)
        af[i] = *(const bf16x8*)&As[(wr * 64 + i * 16 + lm) * 64 + kk * 32 + lq * 8];
#pragma unroll
      for (int jj = 0; jj < 4; ++jj)
        wf[jj] = *(const bf16x8*)&Ws[(wc * 64 + jj * 16 + lm) * 64 + kk * 32 + lq * 8];
#pragma unroll
      for (int i = 0; i < 4; ++i)
#pragma unroll
        for (int jj = 0; jj < 4; ++jj)
          acc[i][jj] = __builtin_amdgcn_mfma_f32_16x16x32_bf16(af[i], wf[jj], acc[i][jj], 0, 0, 0);
    }
  }

  if (!j.tout) {
#pragma unroll
    for (int jj = 0; jj < 4; ++jj) {
      int col = n0 + wc * 64 + jj * 16 + lm;
      float bn = j.bias[col] * j.bscale;
#pragma unroll
      for (int i = 0; i < 4; ++i) {
        int mrow = m0 + wr * 64 + i * 16 + lq * 4;
#pragma unroll
        for (int r = 0; r < 4; ++r) {
          float cv = acc[i][jj][r] + bn;
          if (j.act) cv = 0.5f * cv * (1.0f + erff(cv * 0.70710678118f));
          j.C[(size_t)(mrow + r) * H_ + col] = f2bf(cv);
        }
      }
    }
  } else {
    int b = m0 >> 11;
    int sb = (m0 & (S_ - 1)) + wr * 64;
#pragma unroll
    for (int jj = 0; jj < 4; ++jj) {
      int col = n0 + wc * 64 + jj * 16 + lm;
      float bn = j.bias[col] * j.bscale;
      short* cp = j.C + ((size_t)(b * H_ + col)) * S_;
#pragma unroll
      for (int i = 0; i < 4; ++i) {
        int s = sb + i * 16 + lq * 4;
        s16x4 pk = {f2bf(acc[i][jj][0] + bn), f2bf(acc[i][jj][1] + bn),
                    f2bf(acc[i][jj][2] + bn), f2bf(acc[i][jj][3] + bn)};
        *(s16x4*)(cp + s) = pk;
      }
    }
  }
}

// ---------------------------------------------------------------------------
// Single GEMM, 128x64 tile (768 blocks = 3.0/CU): pw/o/post projections.
// 1D grid, XCD-swizzled (A row-panel locality).
// ---------------------------------------------------------------------------
__global__ __launch_bounds__(256) void gemm_n64(const short* __restrict__ A,
                                                const short* __restrict__ W,
                                                const float* __restrict__ bias,
                                                short* __restrict__ C, int act) {
  int d = blockIdx.x;
  int xcd = d & 7, s5 = d >> 3;            // s5 in [0,96)
  int nx = s5 % 12, ny = xcd + 8 * (s5 / 12);  // ny in [0,64)
  __shared__ short As[128 * 64];  // 16 KB
  __shared__ short Ws[64 * 64];   // 8 KB
  int tid = threadIdx.x, lane = tid & 63, w = tid >> 6;
  int wm = w >> 1, wn = w & 1, lm = lane & 15, lq = lane >> 4;
  int m0 = ny * 128, n0 = nx * 64;
  const short* gA = A + (size_t)(m0 + w * 32 + (lane >> 3)) * H_ + (lane & 7) * 8;
  const short* gW = W + (size_t)(n0 + w * 16 + (lane >> 3)) * H_ + (lane & 7) * 8;
  short* lA = As + w * 2048;  // 32 rows x 64
  short* lW = Ws + w * 1024;  // 16 rows x 64

  f32x4 acc[4][2];
#pragma unroll
  for (int i = 0; i < 4; ++i)
#pragma unroll
    for (int jj = 0; jj < 2; ++jj) acc[i][jj] = (f32x4){0.f, 0.f, 0.f, 0.f};

  for (int kt = 0; kt < H_; kt += 64) {
    __syncthreads();
#pragma unroll
    for (int c = 0; c < 4; ++c)
      gload16(gA + kt + (size_t)(c * 8) * H_, lA + c * 512);
#pragma unroll
    for (int c = 0; c < 2; ++c)
      gload16(gW + kt + (size_t)(c * 8) * H_, lW + c * 512);
    __syncthreads();
#pragma unroll
    for (int kk = 0; kk < 2; ++kk) {
      bf16x8 af[4], wf[2];
#pragma unroll
      for (int i = 0; i < 4; ++i)
        af[i] = *(const bf16x8*)&As[(wm * 64 + i * 16 + lm) * 64 + kk * 32 + lq * 8];
#pragma unroll
      for (int jj = 0; jj < 2; ++jj)
        wf[jj] = *(const bf16x8*)&Ws[(wn * 32 + jj * 16 + lm) * 64 + kk * 32 + lq * 8];
#pragma unroll
      for (int i = 0; i < 4; ++i)
#pragma unroll
        for (int jj = 0; jj < 2; ++jj)
          acc[i][jj] = __builtin_amdgcn_mfma_f32_16x16x32_bf16(af[i], wf[jj], acc[i][jj], 0, 0, 0);
    }
  }

#pragma unroll
  for (int jj = 0; jj < 2; ++jj) {
    int col = n0 + wn * 32 + jj * 16 + lm;
    float bn = bias[col];
#pragma unroll
    for (int i = 0; i < 4; ++i) {
      int mrow = m0 + wm * 64 + i * 16 + lq * 4;
#pragma unroll
      for (int r = 0; r < 4; ++r) {
        float cv = acc[i][jj][r] + bn;
        if (act) cv = 0.5f * cv * (1.0f + erff(cv * 0.70710678118f));
        C[(size_t)(mrow + r) * H_ + col] = f2bf(cv);
      }
    }
  }
}

// ---------------------------------------------------------------------------
// LayerNorm over last dim (H=768), bf16 in -> bf16 out
// ---------------------------------------------------------------------------
__global__ __launch_bounds__(256) void ln_bf(const short* __restrict__ X,
                                             short* __restrict__ Y,
                                             const float* __restrict__ g,
                                             const float* __restrict__ bb) {
  int row = blockIdx.x;
  size_t base = (size_t)row * H_;
  int h0 = threadIdx.x, h1 = h0 + 256, h2 = h0 + 512;
  float x0 = bf2f(X[base + h0]), x1 = bf2f(X[base + h1]), x2 = bf2f(X[base + h2]);
  float s = x0 + x1 + x2;
  float s2 = x0 * x0 + x1 * x1 + x2 * x2;
  for (int off = 32; off > 0; off >>= 1) {
    s += __shfl_down(s, off);
    s2 += __shfl_down(s2, off);
  }
  __shared__ float sa[4], sq[4], st[2];
  int wid = threadIdx.x >> 6, lane = threadIdx.x & 63;
  if (lane == 0) { sa[wid] = s; sq[wid] = s2; }
  __syncthreads();
  if (threadIdx.x == 0) {
    float ts = sa[0] + sa[1] + sa[2] + sa[3];
    float ts2 = sq[0] + sq[1] + sq[2] + sq[3];
    float mean = ts * (1.0f / H_);
    float var = ts2 * (1.0f / H_) - mean * mean;
    st[0] = mean;
    st[1] = rsqrtf(var + 1e-5f);
  }
  __syncthreads();
  float mean = st[0], rstd = st[1];
  Y[base + h0] = f2bf((x0 - mean) * rstd * g[h0] + bb[h0]);
  Y[base + h1] = f2bf((x1 - mean) * rstd * g[h1] + bb[h1]);
  Y[base + h2] = f2bf((x2 - mean) * rstd * g[h2] + bb[h2]);
}

// ---------------------------------------------------------------------------
// MFMA flash attention v8. Changes vs v7:
//  - K/V staging via global_load_lds (DMA) with PRE-SWIZZLED global source
//    (rule #21: linear LDS dest + inverse-swz source + swz read): per-lane
//    source slot jl = (lane&7)^(lane>>3) lands data exactly in the XOR'd
//    layout the (unchanged) read side expects. Deletes 4 ds_write_b128,
//    16 staged VGPRs, and the write-address VALU per wave-tile.
//  - exp2f -> raw v_exp_f32 (__builtin_amdgcn_exp2f): drops ocml's
//    denormal-guard sequence (~5 VALU/exp x 64 exps per wave-tile).
// ---------------------------------------------------------------------------
__global__ __launch_bounds__(256) void attn8_k(const short* __restrict__ qb,
                                               const short* __restrict__ kb,
                                               const short* __restrict__ vtb,
                                               short* __restrict__ aob) {
  __shared__ short Ks[2][64 * 64];     // [sk][d] swizzled, 2 x 8 KB
  __shared__ short Vt[2][64 * 64];     // [d][sk] swizzled, 2 x 8 KB
  int tid = threadIdx.x, lane = tid & 63, w = tid >> 6;  // w 0..3
  int lm = lane & 15, lq = lane >> 4;
  int lm7 = lm & 7;
  // XCD-swizzled decode: g=(b,n) group, all 16 q-blocks of g on one XCD
  int dd = blockIdx.x;
  int xcd = dd & 7, slot = dd >> 3;          // slot in [0,96)
  int g = xcd + 8 * (slot >> 4);             // g in [0,48)
  int qx = slot & 15;
  int b = g / NH_, n = g - b * NH_;
  int q0 = qx * 128;
  int hoff = n * HD_;

  // swizzled fragment slot offsets (in shorts): logical 16B-slot lq / lq+4
  int rb8 = (lq ^ lm7) << 3;
  int rb8x = rb8 ^ 32;

  bf16x8 qf[2][2];
#pragma unroll
  for (int qg = 0; qg < 2; ++qg) {
    const short* qrow = qb + ((size_t)(b * S_ + q0 + w * 32 + qg * 16 + lm)) * H_ + hoff;
    qf[qg][0] = *(const bf16x8*)(qrow + lq * 8);
    qf[qg][1] = *(const bf16x8*)(qrow + 32 + lq * 8);
  }

  // ones A-fragment (bf16 1.0) for MFMA row-sum of P
  bf16x8 onef = {0x3F80, 0x3F80, 0x3F80, 0x3F80, 0x3F80, 0x3F80, 0x3F80, 0x3F80};
  f32x4 ls[2];
  ls[0] = (f32x4){0.f, 0.f, 0.f, 0.f};
  ls[1] = (f32x4){0.f, 0.f, 0.f, 0.f};

  f32x4 o[4][2];
#pragma unroll
  for (int i = 0; i < 4; ++i)
#pragma unroll
    for (int qg = 0; qg < 2; ++qg) o[i][qg] = (f32x4){0.f, 0.f, 0.f, 0.f};

  // DMA staging geometry: wave w, call c covers LDS 16B-slots
  // s = w*128 + c*64 + lane -> row r = w*16 + c*8 + (lane>>3), phys slot lane&7.
  // Phys slot p of row r must hold logical slot p^(r&7); r&7 = lane>>3, so
  // the global source slot is jl = (lane&7)^(lane>>3).
  int jl = ((lane & 7) ^ (lane >> 3)) * 8;   // shorts within the 64-short row
  int rr = w * 16 + (lane >> 3);             // source row for call c=0 (+8 for c=1)
  const short* kgl = kb + ((size_t)(b * S_ + rr)) * H_ + hoff + jl;
  const short* vgl = vtb + ((size_t)(b * H_ + hoff + rr)) * S_ + jl;
  int lbase = w * 1024;                      // shorts: wave's 2KB LDS span

  // prologue: tile 0 -> buf 0
#pragma unroll
  for (int c = 0; c < 2; ++c) {
    gload16(kgl + (size_t)(c * 8) * H_, &Ks[0][lbase + c * 512]);
    gload16(vgl + (size_t)(c * 8) * S_, &Vt[0][lbase + c * 512]);
  }

  for (int kt = 0, pb = 0; kt < S_; kt += 64, pb ^= 1) {
    __syncthreads();  // drains this wave's outstanding DMA -> buf[pb] ready
    if (kt + 64 < S_) {
#pragma unroll
      for (int c = 0; c < 2; ++c) {
        gload16(kgl + (size_t)(kt + 64 + c * 8) * H_, &Ks[pb ^ 1][lbase + c * 512]);
        gload16(vgl + (size_t)(c * 8) * S_ + (kt + 64), &Vt[pb ^ 1][lbase + c * 512]);
      }
    }
    const short* Kw = &Ks[pb][0];
    const short* Vw = &Vt[pb][0];

    // ---- S^T[sk][q]: sk = ni*16 + lq*4 + r, q = lm (per q-group) ----
    f32x4 st[4][2];
    __builtin_amdgcn_s_setprio(1);
#pragma unroll
    for (int ni = 0; ni < 4; ++ni) {
      int krow = (ni * 16 + lm) * 64;
      bf16x8 ka0 = *(const bf16x8*)&Kw[krow + rb8];
      bf16x8 ka1 = *(const bf16x8*)&Kw[krow + rb8x];
#pragma unroll
      for (int qg = 0; qg < 2; ++qg) {
        f32x4 z = (f32x4){0.f, 0.f, 0.f, 0.f};
        z = __builtin_amdgcn_mfma_f32_16x16x32_bf16(ka0, qf[qg][0], z, 0, 0, 0);
        st[ni][qg] = __builtin_amdgcn_mfma_f32_16x16x32_bf16(ka1, qf[qg][1], z, 0, 0, 0);
      }
    }
    __builtin_amdgcn_s_setprio(0);

    // ---- exp (pre-scaled scores) + pack + in-register B-layout xform ----
    bf16x8 pf[2][2];
#pragma unroll
    for (int qg = 0; qg < 2; ++qg) {
      unsigned pw0, pw1, pw2, pw3, pw4, pw5, pw6, pw7;
      {
        float p0 = fexp2(st[0][qg][0]), p1 = fexp2(st[0][qg][1]);
        float p2 = fexp2(st[0][qg][2]), p3 = fexp2(st[0][qg][3]);
        pw0 = bfpack(p0, p1); pw1 = bfpack(p2, p3);
      }
      {
        float p0 = fexp2(st[1][qg][0]), p1 = fexp2(st[1][qg][1]);
        float p2 = fexp2(st[1][qg][2]), p3 = fexp2(st[1][qg][3]);
        pw2 = bfpack(p0, p1); pw3 = bfpack(p2, p3);
      }
      {
        float p0 = fexp2(st[2][qg][0]), p1 = fexp2(st[2][qg][1]);
        float p2 = fexp2(st[2][qg][2]), p3 = fexp2(st[2][qg][3]);
        pw4 = bfpack(p0, p1); pw5 = bfpack(p2, p3);
      }
      {
        float p0 = fexp2(st[3][qg][0]), p1 = fexp2(st[3][qg][1]);
        float p2 = fexp2(st[3][qg][2]), p3 = fexp2(st[3][qg][3]);
        pw6 = bfpack(p0, p1); pw7 = bfpack(p2, p3);
      }
      // chunk 0 (sk 0..31): ni 0,1  -> words j0..j3 across lq groups
      plswap32(pw0, pw2); plswap16(pw0, pw2);   // pw0=j0, pw2=j2
      plswap32(pw1, pw3); plswap16(pw1, pw3);   // pw1=j1, pw3=j3
      // chunk 1 (sk 32..63): ni 2,3
      plswap32(pw4, pw6); plswap16(pw4, pw6);   // pw4=j0, pw6=j2
      plswap32(pw5, pw7); plswap16(pw5, pw7);   // pw5=j1, pw7=j3
      union { u32x4 u; bf16x8 v; } c0u, c1u;
      c0u.u = (u32x4){pw0, pw1, pw2, pw3};
      c1u.u = (u32x4){pw4, pw5, pw6, pw7};
      pf[qg][0] = c0u.v;
      pf[qg][1] = c1u.v;
    }

    // ---- O^T += V^T P^T ; denominator += 1^T P^T (matrix pipe) ----
    __builtin_amdgcn_s_setprio(1);
#pragma unroll
    for (int qg = 0; qg < 2; ++qg) {
      ls[qg] = __builtin_amdgcn_mfma_f32_16x16x32_bf16(onef, pf[qg][0], ls[qg], 0, 0, 0);
      ls[qg] = __builtin_amdgcn_mfma_f32_16x16x32_bf16(onef, pf[qg][1], ls[qg], 0, 0, 0);
    }
#pragma unroll
    for (int nd = 0; nd < 4; ++nd) {
      int vrow = (nd * 16 + lm) * 64;
      bf16x8 va0 = *(const bf16x8*)&Vw[vrow + rb8];
      bf16x8 va1 = *(const bf16x8*)&Vw[vrow + rb8x];
#pragma unroll
      for (int qg = 0; qg < 2; ++qg) {
        o[nd][qg] = __builtin_amdgcn_mfma_f32_16x16x32_bf16(va0, pf[qg][0], o[nd][qg], 0, 0, 0);
        o[nd][qg] = __builtin_amdgcn_mfma_f32_16x16x32_bf16(va1, pf[qg][1], o[nd][qg], 0, 0, 0);
      }
    }
    __builtin_amdgcn_s_setprio(0);
  }

  // epilogue: q row = q0 + w*32 + qg*16 + lm; d = nd*16 + lq*4 + r
#pragma unroll
  for (int qg = 0; qg < 2; ++qg) {
    float inv = 1.0f / ls[qg][0];
    short* orow = aob + ((size_t)(b * S_ + q0 + w * 32 + qg * 16 + lm)) * H_ + hoff;
#pragma unroll
    for (int nd = 0; nd < 4; ++nd) {
      s16x4 pk = {f2bf(o[nd][qg][0] * inv), f2bf(o[nd][qg][1] * inv),
                  f2bf(o[nd][qg][2] * inv), f2bf(o[nd][qg][3] * inv)};
      *(s16x4*)(orow + nd * 16 + lq * 4) = pk;
    }
  }
}

// ---------------------------------------------------------------------------
// gate + masked residual + aux partials. 192 thr, x4 vectorized.
// ---------------------------------------------------------------------------
__global__ __launch_bounds__(192) void gate_out_k(const float* __restrict__ x,
                                                  const short* __restrict__ br,
                                                  const short* __restrict__ inj,
                                                  const int* __restrict__ mask,
                                                  const float* __restrict__ Wg,
                                                  const float* __restrict__ bg,
                                                  float* __restrict__ out,
                                                  float* __restrict__ paux) {
  int row = blockIdx.x;
  int b = row >> 11;
  size_t base = (size_t)row * H_;
  int h = threadIdx.x * 4;
  float4 xv = *(const float4*)(x + base + h);
  s16x4 brv = *(const s16x4*)(br + base + h);
  s16x4 inv = *(const s16x4*)(inj + base + h);
  float4 wg0 = *(const float4*)(Wg + h);
  float4 wg1 = *(const float4*)(Wg + H_ + h);
  float b0 = bf2f(brv.x), b1 = bf2f(brv.y), b2 = bf2f(brv.z), b3 = bf2f(brv.w);
  float dot = xv.x * wg0.x + xv.y * wg0.y + xv.z * wg0.z + xv.w * wg0.w
            + b0 * wg1.x + b1 * wg1.y + b2 * wg1.z + b3 * wg1.w;
  float d0 = b0 - xv.x, d1 = b1 - xv.y, d2 = b2 - xv.z, d3 = b3 - xv.w;
  float aux = d0 * d0 + d1 * d1 + d2 * d2 + d3 * d3;
  for (int off = 32; off > 0; off >>= 1) {
    dot += __shfl_down(dot, off);
    aux += __shfl_down(aux, off);
  }
  __shared__ float sd[3], sx[3], gsh[2];
  int wid = threadIdx.x >> 6, lane = threadIdx.x & 63;
  if (lane == 0) { sd[wid] = dot; sx[wid] = aux; }
  __syncthreads();
  if (threadIdx.x == 0) {
    float td = sd[0] + sd[1] + sd[2];
    float ta = sx[0] + sx[1] + sx[2];
    gsh[0] = 1.0f / (1.0f + expf(-(td + bg[0])));
    gsh[1] = ta;
  }
  __syncthreads();
  float mf = (mask[b] != 0) ? 1.0f : 0.0f;
  float gm = gsh[0] * mf;
  float v0 = bf2f(inv.x), v1 = bf2f(inv.y), v2 = bf2f(inv.z), v3 = bf2f(inv.w);
  float e0 = __expf(2.f * v0), e1 = __expf(2.f * v1), e2 = __expf(2.f * v2), e3 = __expf(2.f * v3);
  float4 ov;
  ov.x = xv.x + gm * ((e0 - 1.f) / (e0 + 1.f));
  ov.y = xv.y + gm * ((e1 - 1.f) / (e1 + 1.f));
  ov.z = xv.z + gm * ((e2 - 1.f) / (e2 + 1.f));
  ov.w = xv.w + gm * ((e3 - 1.f) / (e3 + 1.f));
  *(float4*)(out + base + h) = ov;
  if (threadIdx.x == 0) paux[row] = mf * gsh[1];
}

__global__ __launch_bounds__(256) void aux_reduce_k(const float* __restrict__ paux,
                                                    const int* __restrict__ mask,
                                                    float* __restrict__ outp) {
  float s = 0.f;
  for (int i = threadIdx.x; i < NROWS; i += 256) s += paux[i];
  for (int off = 32; off > 0; off >>= 1) s += __shfl_down(s, off);
  __shared__ float sw[4];
  int wid = threadIdx.x >> 6, lane = threadIdx.x & 63;
  if (lane == 0) sw[wid] = s;
  __syncthreads();
  if (threadIdx.x == 0) {
    float t = sw[0] + sw[1] + sw[2] + sw[3];
    int nm = (mask[0] != 0) + (mask[1] != 0) + (mask[2] != 0) + (mask[3] != 0);
    if (nm < 1) nm = 1;
    outp[0] = t / ((float)nm * (float)(S_ * H_));
  }
}

// ---------------------------------------------------------------------------
extern "C" void kernel_launch(void* const* d_in, const int* in_sizes, int n_in,
                              void* d_out, int out_size, void* d_ws, size_t ws_size,
                              hipStream_t stream) {
  const float* x     = (const float*)d_in[0];
  const float* prev  = (const float*)d_in[1];
  const int*   mask  = (const int*)d_in[2];
  const float* dw_w  = (const float*)d_in[3];
  const float* dw_b  = (const float*)d_in[4];
  const float* pw_w  = (const float*)d_in[5];
  const float* pw_b  = (const float*)d_in[6];
  const float* cn_g  = (const float*)d_in[7];
  const float* cn_b  = (const float*)d_in[8];
  const float* Wq    = (const float*)d_in[9];
  const float* bq    = (const float*)d_in[10];
  const float* Wk    = (const float*)d_in[11];
  const float* bk    = (const float*)d_in[12];
  const float* Wv    = (const float*)d_in[13];
  const float* bv    = (const float*)d_in[14];
  const float* Wo    = (const float*)d_in[15];
  const float* bo    = (const float*)d_in[16];
  const float* pn_g  = (const float*)d_in[17];
  const float* pn_b  = (const float*)d_in[18];
  const float* Wpost = (const float*)d_in[19];
  const float* bpost = (const float*)d_in[20];
  const float* Wg    = (const float*)d_in[21];
  const float* bg    = (const float*)d_in[22];
  float* out = (float*)d_out;

  short* B0 = (short*)d_ws;     // xb
  short* B1 = B0 + BSH;         // dwo -> qb
  short* B2 = B1 + BSH;         // gelu-out -> aob
  short* B3 = B2 + BSH;         // bridged (until gate)
  short* B4 = B3 + BSH;         // kb -> ao_proj -> pn
  short* B5 = B4 + BSH;         // vtb -> injb
  short* WW = B5 + BSH;         // 6 bf16 weights [pw,q,k,v,o,post]
  float* paux = (float*)(WW + 6 * WSZ);

  const float C1 = 0.1803368802f;  // 0.125 * log2(e), folded into Wq/bq

  GemmJob jq = {B0, WW + WSZ,     bq, B1, 0, 0, C1};
  GemmJob jk = {B3, WW + 2 * WSZ, bk, B4, 0, 0, 1.0f};
  GemmJob jv = {B3, WW + 3 * WSZ, bv, B5, 0, 1, 1.0f};

  cvt6_k<<<6 * WSZ / 1024, 256, 0, stream>>>(pw_w, Wq, Wk, Wv, Wo, Wpost, WW);
  cvt_x_k<<<BSH / 1024, 256, 0, stream>>>(x, B0);
  dwconv_k<<<NROWS, 192, 0, stream>>>(prev, dw_w, dw_b, B1);
  gemm_n64<<<768, 256, 0, stream>>>(B1, WW, pw_b, B2, 1);                  // pw + GELU
  ln_bf<<<NROWS, 256, 0, stream>>>(B2, B3, cn_g, cn_b);                    // bridged
  gemm_bf2<<<1152, 256, 0, stream>>>(jq, jk, jv);                          // Q,K,V grouped
  attn8_k<<<768, 256, 0, stream>>>(B1, B4, B5, B2);                        // -> aob
  gemm_n64<<<768, 256, 0, stream>>>(B2, WW + 4 * WSZ, bo, B4, 0);          // o-proj
  ln_bf<<<NROWS, 256, 0, stream>>>(B4, B4, pn_g, pn_b);                    // pn
  gemm_n64<<<768, 256, 0, stream>>>(B4, WW + 5 * WSZ, bpost, B5, 0);       // post
  gate_out_k<<<NROWS, 192, 0, stream>>>(x, B3, B5, mask, Wg, bg, out, paux);
  aux_reduce_k<<<1, 256, 0, stream>>>(paux, mask, out + BSH);
}

// Round 6
// 369.405 us; speedup vs baseline: 1.0593x; 1.0077x over previous
//
#include <hip/hip_runtime.h>
#include <math.h>

#define B_ 4
#define S_ 2048
#define H_ 768
#define NH_ 12
#define HD_ 64
#define BSH (B_ * S_ * H_)
#define NROWS (B_ * S_)
#define WSZ (H_ * H_)  // 589824

typedef __attribute__((ext_vector_type(8))) short bf16x8;
typedef __attribute__((ext_vector_type(4))) short s16x4;
typedef __attribute__((ext_vector_type(4))) float f32x4;
typedef __attribute__((ext_vector_type(2))) unsigned u32x2;
typedef __attribute__((ext_vector_type(4))) unsigned u32x4;

__device__ __forceinline__ short f2bf(float f) {
  union { float f; unsigned u; } x; x.f = f;
  unsigned r = x.u + 0x7FFF + ((x.u >> 16) & 1);
  return (short)(r >> 16);
}
__device__ __forceinline__ float bf2f(short s) {
  union { unsigned u; float f; } x;
  x.u = ((unsigned)(unsigned short)s) << 16;
  return x.f;
}
// pack 2 fp32 -> 2 bf16 (truncation) in one v_perm_b32
__device__ __forceinline__ unsigned bfpack(float lo, float hi) {
  union { float f; unsigned u; } a, b; a.f = lo; b.f = hi;
  return __builtin_amdgcn_perm(b.u, a.u, 0x07060302);
}

// raw v_exp_f32 (scores are range-bounded; skip ocml denormal guards)
__device__ __forceinline__ float fexp2(float x) {
#if __has_builtin(__builtin_amdgcn_exp2f)
  return __builtin_amdgcn_exp2f(x);
#else
  float r;
  asm("v_exp_f32 %0, %1" : "=v"(r) : "v"(x));
  return r;
#endif
}

// permlane swaps, hardened: builtin if available, else inline asm
__device__ __forceinline__ void plswap32(unsigned& a, unsigned& b) {
#if __has_builtin(__builtin_amdgcn_permlane32_swap)
  u32x2 r = __builtin_amdgcn_permlane32_swap(a, b, false, false);
  a = r.x; b = r.y;
#else
  asm volatile("v_permlane32_swap_b32 %0, %1" : "+v"(a), "+v"(b));
#endif
}
__device__ __forceinline__ void plswap16(unsigned& a, unsigned& b) {
#if __has_builtin(__builtin_amdgcn_permlane16_swap)
  u32x2 r = __builtin_amdgcn_permlane16_swap(a, b, false, false);
  a = r.x; b = r.y;
#else
  asm volatile("v_permlane16_swap_b32 %0, %1" : "+v"(a), "+v"(b));
#endif
}

// async global->LDS, 16B per lane; LDS dst = wave-uniform base + lane*16
typedef __attribute__((address_space(1))) const unsigned int g_u32;
typedef __attribute__((address_space(3))) unsigned int l_u32;
__device__ __forceinline__ void gload16(const void* g, void* l) {
  __builtin_amdgcn_global_load_lds((g_u32*)g, (l_u32*)l, 16, 0, 0);
}

// ---------------------------------------------------------------------------
// fp32 -> bf16 converters
// ---------------------------------------------------------------------------
__global__ __launch_bounds__(256) void cvt_x_k(const float* __restrict__ src,
                                               short* __restrict__ dst) {
  int i = (blockIdx.x * 256 + threadIdx.x) * 4;
  float4 v = *(const float4*)(src + i);
  s16x4 o = {f2bf(v.x), f2bf(v.y), f2bf(v.z), f2bf(v.w)};
  *(s16x4*)(dst + i) = o;
}

// w1 (Wq) is pre-scaled by C1 = 0.125*log2(e) so attn can exp2 scores directly
__global__ __launch_bounds__(256) void cvt6_k(const float* w0, const float* w1,
                                              const float* w2, const float* w3,
                                              const float* w4, const float* w5,
                                              short* __restrict__ dst) {
  int i = (blockIdx.x * 256 + threadIdx.x) * 4;
  int m = i / WSZ;
  int off = i - m * WSZ;
  const float* s = m == 0 ? w0 : m == 1 ? w1 : m == 2 ? w2 : m == 3 ? w3 : m == 4 ? w4 : w5;
  float sc = (m == 1) ? 0.1803368802f : 1.0f;
  float4 v = *(const float4*)(s + off);
  s16x4 o = {f2bf(v.x * sc), f2bf(v.y * sc), f2bf(v.z * sc), f2bf(v.w * sc)};
  *(s16x4*)(dst + i) = o;
}

// ---------------------------------------------------------------------------
// depthwise conv1d k=3 pad=1 over seq; vectorized x4, 192 thr (H/4=192)
// ---------------------------------------------------------------------------
__global__ __launch_bounds__(192) void dwconv_k(const float* __restrict__ prev,
                                                const float* __restrict__ w3,
                                                const float* __restrict__ bias,
                                                short* __restrict__ out) {
  int row = blockIdx.x;
  int s = row & (S_ - 1);
  int h = threadIdx.x * 4;
  size_t base = (size_t)row * H_ + h;
  float4 c = *(const float4*)(prev + base);
  float4 wa = *(const float4*)(w3 + h * 3);
  float4 wb = *(const float4*)(w3 + h * 3 + 4);
  float4 wc = *(const float4*)(w3 + h * 3 + 8);
  float4 bi = *(const float4*)(bias + h);
  float4 acc;
  acc.x = bi.x + c.x * wa.y;
  acc.y = bi.y + c.y * wb.x;
  acc.z = bi.z + c.z * wb.w;
  acc.w = bi.w + c.w * wc.z;
  if (s > 0) {
    float4 l = *(const float4*)(prev + base - H_);
    acc.x += l.x * wa.x; acc.y += l.y * wa.w; acc.z += l.z * wb.z; acc.w += l.w * wc.y;
  }
  if (s < S_ - 1) {
    float4 r = *(const float4*)(prev + base + H_);
    acc.x += r.x * wa.z; acc.y += r.y * wb.y; acc.z += r.z * wc.x; acc.w += r.w * wc.w;
  }
  s16x4 o = {f2bf(acc.x), f2bf(acc.y), f2bf(acc.z), f2bf(acc.w)};
  *(s16x4*)(out + base) = o;
}

// ---------------------------------------------------------------------------
// Grouped GEMM (QKV): 128x128 tiles, BK=64. 1D grid, XCD-swizzled.
// v2: attn8-style staging — double-buffered LDS, ONE barrier per K-step,
// pre-swizzled DMA source (jl = (lane&7)^(lane>>3)) + swizzled reads:
// kills the 1.06e7 bank conflicts and overlaps DMA latency with MFMA.
// ---------------------------------------------------------------------------
struct GemmJob {
  const short* A; const short* W; const float* bias; short* C; int act; int tout;
  float bscale;
};

__global__ __launch_bounds__(256) void gemm_bf2(GemmJob j0, GemmJob j1, GemmJob j2) {
  int d = blockIdx.x;
  int z = d / 384, r5 = d - z * 384;
  GemmJob j = z == 0 ? j0 : (z == 1 ? j1 : j2);
  int xcd = r5 & 7, s5 = r5 >> 3;          // s5 in [0,48)
  int nx = s5 % 6, ny = xcd + 8 * (s5 / 6);  // ny in [0,64)
  __shared__ short As[2][128 * 64];  // 2 x 16 KB
  __shared__ short Ws[2][128 * 64];  // 2 x 16 KB
  int tid = threadIdx.x, lane = tid & 63, w = tid >> 6;
  int wr = w >> 1, wc = w & 1, lm = lane & 15, lq = lane >> 4;
  int lm7 = lm & 7;
  int rb8 = (lq ^ lm7) << 3, rb8x = rb8 ^ 32;
  int m0 = ny * 128, n0 = nx * 128;
  int srow = lane >> 3;
  int jl = ((lane & 7) ^ srow) * 8;   // pre-swizzled source slot
  const short* gA = j.A + (size_t)(m0 + w * 32 + srow) * H_ + jl;
  const short* gW = j.W + (size_t)(n0 + w * 32 + srow) * H_ + jl;
  int lbase = w * 2048;

  f32x4 acc[4][4];
#pragma unroll
  for (int i = 0; i < 4; ++i)
#pragma unroll
    for (int jj = 0; jj < 4; ++jj) acc[i][jj] = (f32x4){0.f, 0.f, 0.f, 0.f};

  // prologue: K-step 0 -> buf 0
#pragma unroll
  for (int c = 0; c < 4; ++c) {
    gload16(gA + (size_t)(c * 8) * H_, &As[0][lbase + c * 512]);
    gload16(gW + (size_t)(c * 8) * H_, &Ws[0][lbase + c * 512]);
  }

  for (int kt = 0, pb = 0; kt < H_; kt += 64, pb ^= 1) {
    __syncthreads();  // drains DMA -> buf[pb] ready
    if (kt + 64 < H_) {
#pragma unroll
      for (int c = 0; c < 4; ++c) {
        gload16(gA + kt + 64 + (size_t)(c * 8) * H_, &As[pb ^ 1][lbase + c * 512]);
        gload16(gW + kt + 64 + (size_t)(c * 8) * H_, &Ws[pb ^ 1][lbase + c * 512]);
      }
    }
    const short* Aw = &As[pb][0];
    const short* Ww = &Ws[pb][0];
#pragma unroll
    for (int kk = 0; kk < 2; ++kk) {
      int ro = kk ? rb8x : rb8;
      bf16x8 af[4], wf[4];
#pragma unroll
      for (int i = 0; i < 4; ++i)
        af[i] = *(const bf16x8*)&Aw[(wr * 64 + i * 16 + lm) * 64 + ro];
#pragma unroll
      for (int jj = 0; jj < 4; ++jj)
        wf[jj] = *(const bf16x8*)&Ww[(wc * 64 + jj * 16 + lm) * 64 + ro];
#pragma unroll
      for (int i = 0; i < 4; ++i)
#pragma unroll
        for (int jj = 0; jj < 4; ++jj)
          acc[i][jj] = __builtin_amdgcn_mfma_f32_16x16x32_bf16(af[i], wf[jj], acc[i][jj], 0, 0, 0);
    }
  }

  if (!j.tout) {
#pragma unroll
    for (int jj = 0; jj < 4; ++jj) {
      int col = n0 + wc * 64 + jj * 16 + lm;
      float bn = j.bias[col] * j.bscale;
#pragma unroll
      for (int i = 0; i < 4; ++i) {
        int mrow = m0 + wr * 64 + i * 16 + lq * 4;
#pragma unroll
        for (int r = 0; r < 4; ++r) {
          float cv = acc[i][jj][r] + bn;
          if (j.act) cv = 0.5f * cv * (1.0f + erff(cv * 0.70710678118f));
          j.C[(size_t)(mrow + r) * H_ + col] = f2bf(cv);
        }
      }
    }
  } else {
    int b = m0 >> 11;
    int sb = (m0 & (S_ - 1)) + wr * 64;
#pragma unroll
    for (int jj = 0; jj < 4; ++jj) {
      int col = n0 + wc * 64 + jj * 16 + lm;
      float bn = j.bias[col] * j.bscale;
      short* cp = j.C + ((size_t)(b * H_ + col)) * S_;
#pragma unroll
      for (int i = 0; i < 4; ++i) {
        int s = sb + i * 16 + lq * 4;
        s16x4 pk = {f2bf(acc[i][jj][0] + bn), f2bf(acc[i][jj][1] + bn),
                    f2bf(acc[i][jj][2] + bn), f2bf(acc[i][jj][3] + bn)};
        *(s16x4*)(cp + s) = pk;
      }
    }
  }
}

// ---------------------------------------------------------------------------
// Single GEMM, 128x64 tile: pw/o/post projections. 1D grid, XCD-swizzled.
// v2: same dbuf + swizzle staging as gemm_bf2. LDS 48 KB -> 3 blocks/CU.
// ---------------------------------------------------------------------------
__global__ __launch_bounds__(256) void gemm_n64(const short* __restrict__ A,
                                                const short* __restrict__ W,
                                                const float* __restrict__ bias,
                                                short* __restrict__ C, int act) {
  int d = blockIdx.x;
  int xcd = d & 7, s5 = d >> 3;            // s5 in [0,96)
  int nx = s5 % 12, ny = xcd + 8 * (s5 / 12);  // ny in [0,64)
  __shared__ short As[2][128 * 64];  // 2 x 16 KB
  __shared__ short Ws[2][64 * 64];   // 2 x 8 KB
  int tid = threadIdx.x, lane = tid & 63, w = tid >> 6;
  int wm = w >> 1, wn = w & 1, lm = lane & 15, lq = lane >> 4;
  int lm7 = lm & 7;
  int rb8 = (lq ^ lm7) << 3, rb8x = rb8 ^ 32;
  int m0 = ny * 128, n0 = nx * 64;
  int srow = lane >> 3;
  int jl = ((lane & 7) ^ srow) * 8;
  const short* gA = A + (size_t)(m0 + w * 32 + srow) * H_ + jl;
  const short* gW = W + (size_t)(n0 + w * 16 + srow) * H_ + jl;
  int lbaseA = w * 2048;  // 32 rows x 64
  int lbaseW = w * 1024;  // 16 rows x 64

  f32x4 acc[4][2];
#pragma unroll
  for (int i = 0; i < 4; ++i)
#pragma unroll
    for (int jj = 0; jj < 2; ++jj) acc[i][jj] = (f32x4){0.f, 0.f, 0.f, 0.f};

  // prologue: K-step 0 -> buf 0
#pragma unroll
  for (int c = 0; c < 4; ++c)
    gload16(gA + (size_t)(c * 8) * H_, &As[0][lbaseA + c * 512]);
#pragma unroll
  for (int c = 0; c < 2; ++c)
    gload16(gW + (size_t)(c * 8) * H_, &Ws[0][lbaseW + c * 512]);

  for (int kt = 0, pb = 0; kt < H_; kt += 64, pb ^= 1) {
    __syncthreads();
    if (kt + 64 < H_) {
#pragma unroll
      for (int c = 0; c < 4; ++c)
        gload16(gA + kt + 64 + (size_t)(c * 8) * H_, &As[pb ^ 1][lbaseA + c * 512]);
#pragma unroll
      for (int c = 0; c < 2; ++c)
        gload16(gW + kt + 64 + (size_t)(c * 8) * H_, &Ws[pb ^ 1][lbaseW + c * 512]);
    }
    const short* Aw = &As[pb][0];
    const short* Ww = &Ws[pb][0];
#pragma unroll
    for (int kk = 0; kk < 2; ++kk) {
      int ro = kk ? rb8x : rb8;
      bf16x8 af[4], wf[2];
#pragma unroll
      for (int i = 0; i < 4; ++i)
        af[i] = *(const bf16x8*)&Aw[(wm * 64 + i * 16 + lm) * 64 + ro];
#pragma unroll
      for (int jj = 0; jj < 2; ++jj)
        wf[jj] = *(const bf16x8*)&Ww[(wn * 32 + jj * 16 + lm) * 64 + ro];
#pragma unroll
      for (int i = 0; i < 4; ++i)
#pragma unroll
        for (int jj = 0; jj < 2; ++jj)
          acc[i][jj] = __builtin_amdgcn_mfma_f32_16x16x32_bf16(af[i], wf[jj], acc[i][jj], 0, 0, 0);
    }
  }

#pragma unroll
  for (int jj = 0; jj < 2; ++jj) {
    int col = n0 + wn * 32 + jj * 16 + lm;
    float bn = bias[col];
#pragma unroll
    for (int i = 0; i < 4; ++i) {
      int mrow = m0 + wm * 64 + i * 16 + lq * 4;
#pragma unroll
      for (int r = 0; r < 4; ++r) {
        float cv = acc[i][jj][r] + bn;
        if (act) cv = 0.5f * cv * (1.0f + erff(cv * 0.70710678118f));
        C[(size_t)(mrow + r) * H_ + col] = f2bf(cv);
      }
    }
  }
}

// ---------------------------------------------------------------------------
// LayerNorm over last dim (H=768), bf16 in -> bf16 out
// ---------------------------------------------------------------------------
__global__ __launch_bounds__(256) void ln_bf(const short* __restrict__ X,
                                             short* __restrict__ Y,
                                             const float* __restrict__ g,
                                             const float* __restrict__ bb) {
  int row = blockIdx.x;
  size_t base = (size_t)row * H_;
  int h0 = threadIdx.x, h1 = h0 + 256, h2 = h0 + 512;
  float x0 = bf2f(X[base + h0]), x1 = bf2f(X[base + h1]), x2 = bf2f(X[base + h2]);
  float s = x0 + x1 + x2;
  float s2 = x0 * x0 + x1 * x1 + x2 * x2;
  for (int off = 32; off > 0; off >>= 1) {
    s += __shfl_down(s, off);
    s2 += __shfl_down(s2, off);
  }
  __shared__ float sa[4], sq[4], st[2];
  int wid = threadIdx.x >> 6, lane = threadIdx.x & 63;
  if (lane == 0) { sa[wid] = s; sq[wid] = s2; }
  __syncthreads();
  if (threadIdx.x == 0) {
    float ts = sa[0] + sa[1] + sa[2] + sa[3];
    float ts2 = sq[0] + sq[1] + sq[2] + sq[3];
    float mean = ts * (1.0f / H_);
    float var = ts2 * (1.0f / H_) - mean * mean;
    st[0] = mean;
    st[1] = rsqrtf(var + 1e-5f);
  }
  __syncthreads();
  float mean = st[0], rstd = st[1];
  Y[base + h0] = f2bf((x0 - mean) * rstd * g[h0] + bb[h0]);
  Y[base + h1] = f2bf((x1 - mean) * rstd * g[h1] + bb[h1]);
  Y[base + h2] = f2bf((x2 - mean) * rstd * g[h2] + bb[h2]);
}

// ---------------------------------------------------------------------------
// MFMA flash attention v8 (unchanged from R5: DMA+preswizzle staging, raw
// v_exp, permlane P-transform, XCD swizzle, setprio).
// ---------------------------------------------------------------------------
__global__ __launch_bounds__(256) void attn8_k(const short* __restrict__ qb,
                                               const short* __restrict__ kb,
                                               const short* __restrict__ vtb,
                                               short* __restrict__ aob) {
  __shared__ short Ks[2][64 * 64];     // [sk][d] swizzled, 2 x 8 KB
  __shared__ short Vt[2][64 * 64];     // [d][sk] swizzled, 2 x 8 KB
  int tid = threadIdx.x, lane = tid & 63, w = tid >> 6;  // w 0..3
  int lm = lane & 15, lq = lane >> 4;
  int lm7 = lm & 7;
  int dd = blockIdx.x;
  int xcd = dd & 7, slot = dd >> 3;          // slot in [0,96)
  int g = xcd + 8 * (slot >> 4);             // g in [0,48)
  int qx = slot & 15;
  int b = g / NH_, n = g - b * NH_;
  int q0 = qx * 128;
  int hoff = n * HD_;

  int rb8 = (lq ^ lm7) << 3;
  int rb8x = rb8 ^ 32;

  bf16x8 qf[2][2];
#pragma unroll
  for (int qg = 0; qg < 2; ++qg) {
    const short* qrow = qb + ((size_t)(b * S_ + q0 + w * 32 + qg * 16 + lm)) * H_ + hoff;
    qf[qg][0] = *(const bf16x8*)(qrow + lq * 8);
    qf[qg][1] = *(const bf16x8*)(qrow + 32 + lq * 8);
  }

  bf16x8 onef = {0x3F80, 0x3F80, 0x3F80, 0x3F80, 0x3F80, 0x3F80, 0x3F80, 0x3F80};
  f32x4 ls[2];
  ls[0] = (f32x4){0.f, 0.f, 0.f, 0.f};
  ls[1] = (f32x4){0.f, 0.f, 0.f, 0.f};

  f32x4 o[4][2];
#pragma unroll
  for (int i = 0; i < 4; ++i)
#pragma unroll
    for (int qg = 0; qg < 2; ++qg) o[i][qg] = (f32x4){0.f, 0.f, 0.f, 0.f};

  int jl = ((lane & 7) ^ (lane >> 3)) * 8;
  int rr = w * 16 + (lane >> 3);
  const short* kgl = kb + ((size_t)(b * S_ + rr)) * H_ + hoff + jl;
  const short* vgl = vtb + ((size_t)(b * H_ + hoff + rr)) * S_ + jl;
  int lbase = w * 1024;

#pragma unroll
  for (int c = 0; c < 2; ++c) {
    gload16(kgl + (size_t)(c * 8) * H_, &Ks[0][lbase + c * 512]);
    gload16(vgl + (size_t)(c * 8) * S_, &Vt[0][lbase + c * 512]);
  }

  for (int kt = 0, pb = 0; kt < S_; kt += 64, pb ^= 1) {
    __syncthreads();
    if (kt + 64 < S_) {
#pragma unroll
      for (int c = 0; c < 2; ++c) {
        gload16(kgl + (size_t)(kt + 64 + c * 8) * H_, &Ks[pb ^ 1][lbase + c * 512]);
        gload16(vgl + (size_t)(c * 8) * S_ + (kt + 64), &Vt[pb ^ 1][lbase + c * 512]);
      }
    }
    const short* Kw = &Ks[pb][0];
    const short* Vw = &Vt[pb][0];

    f32x4 st[4][2];
    __builtin_amdgcn_s_setprio(1);
#pragma unroll
    for (int ni = 0; ni < 4; ++ni) {
      int krow = (ni * 16 + lm) * 64;
      bf16x8 ka0 = *(const bf16x8*)&Kw[krow + rb8];
      bf16x8 ka1 = *(const bf16x8*)&Kw[krow + rb8x];
#pragma unroll
      for (int qg = 0; qg < 2; ++qg) {
        f32x4 z = (f32x4){0.f, 0.f, 0.f, 0.f};
        z = __builtin_amdgcn_mfma_f32_16x16x32_bf16(ka0, qf[qg][0], z, 0, 0, 0);
        st[ni][qg] = __builtin_amdgcn_mfma_f32_16x16x32_bf16(ka1, qf[qg][1], z, 0, 0, 0);
      }
    }
    __builtin_amdgcn_s_setprio(0);

    bf16x8 pf[2][2];
#pragma unroll
    for (int qg = 0; qg < 2; ++qg) {
      unsigned pw0, pw1, pw2, pw3, pw4, pw5, pw6, pw7;
      {
        float p0 = fexp2(st[0][qg][0]), p1 = fexp2(st[0][qg][1]);
        float p2 = fexp2(st[0][qg][2]), p3 = fexp2(st[0][qg][3]);
        pw0 = bfpack(p0, p1); pw1 = bfpack(p2, p3);
      }
      {
        float p0 = fexp2(st[1][qg][0]), p1 = fexp2(st[1][qg][1]);
        float p2 = fexp2(st[1][qg][2]), p3 = fexp2(st[1][qg][3]);
        pw2 = bfpack(p0, p1); pw3 = bfpack(p2, p3);
      }
      {
        float p0 = fexp2(st[2][qg][0]), p1 = fexp2(st[2][qg][1]);
        float p2 = fexp2(st[2][qg][2]), p3 = fexp2(st[2][qg][3]);
        pw4 = bfpack(p0, p1); pw5 = bfpack(p2, p3);
      }
      {
        float p0 = fexp2(st[3][qg][0]), p1 = fexp2(st[3][qg][1]);
        float p2 = fexp2(st[3][qg][2]), p3 = fexp2(st[3][qg][3]);
        pw6 = bfpack(p0, p1); pw7 = bfpack(p2, p3);
      }
      plswap32(pw0, pw2); plswap16(pw0, pw2);
      plswap32(pw1, pw3); plswap16(pw1, pw3);
      plswap32(pw4, pw6); plswap16(pw4, pw6);
      plswap32(pw5, pw7); plswap16(pw5, pw7);
      union { u32x4 u; bf16x8 v; } c0u, c1u;
      c0u.u = (u32x4){pw0, pw1, pw2, pw3};
      c1u.u = (u32x4){pw4, pw5, pw6, pw7};
      pf[qg][0] = c0u.v;
      pf[qg][1] = c1u.v;
    }

    __builtin_amdgcn_s_setprio(1);
#pragma unroll
    for (int qg = 0; qg < 2; ++qg) {
      ls[qg] = __builtin_amdgcn_mfma_f32_16x16x32_bf16(onef, pf[qg][0], ls[qg], 0, 0, 0);
      ls[qg] = __builtin_amdgcn_mfma_f32_16x16x32_bf16(onef, pf[qg][1], ls[qg], 0, 0, 0);
    }
#pragma unroll
    for (int nd = 0; nd < 4; ++nd) {
      int vrow = (nd * 16 + lm) * 64;
      bf16x8 va0 = *(const bf16x8*)&Vw[vrow + rb8];
      bf16x8 va1 = *(const bf16x8*)&Vw[vrow + rb8x];
#pragma unroll
      for (int qg = 0; qg < 2; ++qg) {
        o[nd][qg] = __builtin_amdgcn_mfma_f32_16x16x32_bf16(va0, pf[qg][0], o[nd][qg], 0, 0, 0);
        o[nd][qg] = __builtin_amdgcn_mfma_f32_16x16x32_bf16(va1, pf[qg][1], o[nd][qg], 0, 0, 0);
      }
    }
    __builtin_amdgcn_s_setprio(0);
  }

#pragma unroll
  for (int qg = 0; qg < 2; ++qg) {
    float inv = 1.0f / ls[qg][0];
    short* orow = aob + ((size_t)(b * S_ + q0 + w * 32 + qg * 16 + lm)) * H_ + hoff;
#pragma unroll
    for (int nd = 0; nd < 4; ++nd) {
      s16x4 pk = {f2bf(o[nd][qg][0] * inv), f2bf(o[nd][qg][1] * inv),
                  f2bf(o[nd][qg][2] * inv), f2bf(o[nd][qg][3] * inv)};
      *(s16x4*)(orow + nd * 16 + lq * 4) = pk;
    }
  }
}

// ---------------------------------------------------------------------------
// gate + masked residual + aux partials. 192 thr, x4 vectorized.
// ---------------------------------------------------------------------------
__global__ __launch_bounds__(192) void gate_out_k(const float* __restrict__ x,
                                                  const short* __restrict__ br,
                                                  const short* __restrict__ inj,
                                                  const int* __restrict__ mask,
                                                  const float* __restrict__ Wg,
                                                  const float* __restrict__ bg,
                                                  float* __restrict__ out,
                                                  float* __restrict__ paux) {
  int row = blockIdx.x;
  int b = row >> 11;
  size_t base = (size_t)row * H_;
  int h = threadIdx.x * 4;
  float4 xv = *(const float4*)(x + base + h);
  s16x4 brv = *(const s16x4*)(br + base + h);
  s16x4 inv = *(const s16x4*)(inj + base + h);
  float4 wg0 = *(const float4*)(Wg + h);
  float4 wg1 = *(const float4*)(Wg + H_ + h);
  float b0 = bf2f(brv.x), b1 = bf2f(brv.y), b2 = bf2f(brv.z), b3 = bf2f(brv.w);
  float dot = xv.x * wg0.x + xv.y * wg0.y + xv.z * wg0.z + xv.w * wg0.w
            + b0 * wg1.x + b1 * wg1.y + b2 * wg1.z + b3 * wg1.w;
  float d0 = b0 - xv.x, d1 = b1 - xv.y, d2 = b2 - xv.z, d3 = b3 - xv.w;
  float aux = d0 * d0 + d1 * d1 + d2 * d2 + d3 * d3;
  for (int off = 32; off > 0; off >>= 1) {
    dot += __shfl_down(dot, off);
    aux += __shfl_down(aux, off);
  }
  __shared__ float sd[3], sx[3], gsh[2];
  int wid = threadIdx.x >> 6, lane = threadIdx.x & 63;
  if (lane == 0) { sd[wid] = dot; sx[wid] = aux; }
  __syncthreads();
  if (threadIdx.x == 0) {
    float td = sd[0] + sd[1] + sd[2];
    float ta = sx[0] + sx[1] + sx[2];
    gsh[0] = 1.0f / (1.0f + expf(-(td + bg[0])));
    gsh[1] = ta;
  }
  __syncthreads();
  float mf = (mask[b] != 0) ? 1.0f : 0.0f;
  float gm = gsh[0] * mf;
  float v0 = bf2f(inv.x), v1 = bf2f(inv.y), v2 = bf2f(inv.z), v3 = bf2f(inv.w);
  float e0 = __expf(2.f * v0), e1 = __expf(2.f * v1), e2 = __expf(2.f * v2), e3 = __expf(2.f * v3);
  float4 ov;
  ov.x = xv.x + gm * ((e0 - 1.f) / (e0 + 1.f));
  ov.y = xv.y + gm * ((e1 - 1.f) / (e1 + 1.f));
  ov.z = xv.z + gm * ((e2 - 1.f) / (e2 + 1.f));
  ov.w = xv.w + gm * ((e3 - 1.f) / (e3 + 1.f));
  *(float4*)(out + base + h) = ov;
  if (threadIdx.x == 0) paux[row] = mf * gsh[1];
}

__global__ __launch_bounds__(256) void aux_reduce_k(const float* __restrict__ paux,
                                                    const int* __restrict__ mask,
                                                    float* __restrict__ outp) {
  float s = 0.f;
  for (int i = threadIdx.x; i < NROWS; i += 256) s += paux[i];
  for (int off = 32; off > 0; off >>= 1) s += __shfl_down(s, off);
  __shared__ float sw[4];
  int wid = threadIdx.x >> 6, lane = threadIdx.x & 63;
  if (lane == 0) sw[wid] = s;
  __syncthreads();
  if (threadIdx.x == 0) {
    float t = sw[0] + sw[1] + sw[2] + sw[3];
    int nm = (mask[0] != 0) + (mask[1] != 0) + (mask[2] != 0) + (mask[3] != 0);
    if (nm < 1) nm = 1;
    outp[0] = t / ((float)nm * (float)(S_ * H_));
  }
}

// ---------------------------------------------------------------------------
extern "C" void kernel_launch(void* const* d_in, const int* in_sizes, int n_in,
                              void* d_out, int out_size, void* d_ws, size_t ws_size,
                              hipStream_t stream) {
  const float* x     = (const float*)d_in[0];
  const float* prev  = (const float*)d_in[1];
  const int*   mask  = (const int*)d_in[2];
  const float* dw_w  = (const float*)d_in[3];
  const float* dw_b  = (const float*)d_in[4];
  const float* pw_w  = (const float*)d_in[5];
  const float* pw_b  = (const float*)d_in[6];
  const float* cn_g  = (const float*)d_in[7];
  const float* cn_b  = (const float*)d_in[8];
  const float* Wq    = (const float*)d_in[9];
  const float* bq    = (const float*)d_in[10];
  const float* Wk    = (const float*)d_in[11];
  const float* bk    = (const float*)d_in[12];
  const float* Wv    = (const float*)d_in[13];
  const float* bv    = (const float*)d_in[14];
  const float* Wo    = (const float*)d_in[15];
  const float* bo    = (const float*)d_in[16];
  const float* pn_g  = (const float*)d_in[17];
  const float* pn_b  = (const float*)d_in[18];
  const float* Wpost = (const float*)d_in[19];
  const float* bpost = (const float*)d_in[20];
  const float* Wg    = (const float*)d_in[21];
  const float* bg    = (const float*)d_in[22];
  float* out = (float*)d_out;

  short* B0 = (short*)d_ws;     // xb
  short* B1 = B0 + BSH;         // dwo -> qb
  short* B2 = B1 + BSH;         // gelu-out -> aob
  short* B3 = B2 + BSH;         // bridged (until gate)
  short* B4 = B3 + BSH;         // kb -> ao_proj -> pn
  short* B5 = B4 + BSH;         // vtb -> injb
  short* WW = B5 + BSH;         // 6 bf16 weights [pw,q,k,v,o,post]
  float* paux = (float*)(WW + 6 * WSZ);

  const float C1 = 0.1803368802f;  // 0.125 * log2(e), folded into Wq/bq

  GemmJob jq = {B0, WW + WSZ,     bq, B1, 0, 0, C1};
  GemmJob jk = {B3, WW + 2 * WSZ, bk, B4, 0, 0, 1.0f};
  GemmJob jv = {B3, WW + 3 * WSZ, bv, B5, 0, 1, 1.0f};

  cvt6_k<<<6 * WSZ / 1024, 256, 0, stream>>>(pw_w, Wq, Wk, Wv, Wo, Wpost, WW);
  cvt_x_k<<<BSH / 1024, 256, 0, stream>>>(x, B0);
  dwconv_k<<<NROWS, 192, 0, stream>>>(prev, dw_w, dw_b, B1);
  gemm_n64<<<768, 256, 0, stream>>>(B1, WW, pw_b, B2, 1);                  // pw + GELU
  ln_bf<<<NROWS, 256, 0, stream>>>(B2, B3, cn_g, cn_b);                    // bridged
  gemm_bf2<<<1152, 256, 0, stream>>>(jq, jk, jv);                          // Q,K,V grouped
  attn8_k<<<768, 256, 0, stream>>>(B1, B4, B5, B2);                        // -> aob
  gemm_n64<<<768, 256, 0, stream>>>(B2, WW + 4 * WSZ, bo, B4, 0);          // o-proj
  ln_bf<<<NROWS, 256, 0, stream>>>(B4, B4, pn_g, pn_b);                    // pn
  gemm_n64<<<768, 256, 0, stream>>>(B4, WW + 5 * WSZ, bpost, B5, 0);       // post
  gate_out_k<<<NROWS, 192, 0, stream>>>(x, B3, B5, mask, Wg, bg, out, paux);
  aux_reduce_k<<<1, 256, 0, stream>>>(paux, mask, out + BSH);
}

// Round 7
// 358.886 us; speedup vs baseline: 1.0904x; 1.0293x over previous
//
#include <hip/hip_runtime.h>
#include <math.h>

#define B_ 4
#define S_ 2048
#define H_ 768
#define NH_ 12
#define HD_ 64
#define BSH (B_ * S_ * H_)
#define NROWS (B_ * S_)
#define WSZ (H_ * H_)  // 589824

typedef __attribute__((ext_vector_type(8))) short bf16x8;
typedef __attribute__((ext_vector_type(4))) short s16x4;
typedef __attribute__((ext_vector_type(4))) float f32x4;
typedef __attribute__((ext_vector_type(2))) unsigned u32x2;
typedef __attribute__((ext_vector_type(4))) unsigned u32x4;

__device__ __forceinline__ short f2bf(float f) {
  union { float f; unsigned u; } x; x.f = f;
  unsigned r = x.u + 0x7FFF + ((x.u >> 16) & 1);
  return (short)(r >> 16);
}
__device__ __forceinline__ float bf2f(short s) {
  union { unsigned u; float f; } x;
  x.u = ((unsigned)(unsigned short)s) << 16;
  return x.f;
}
// pack 2 fp32 -> 2 bf16 (truncation) in one v_perm_b32
__device__ __forceinline__ unsigned bfpack(float lo, float hi) {
  union { float f; unsigned u; } a, b; a.f = lo; b.f = hi;
  return __builtin_amdgcn_perm(b.u, a.u, 0x07060302);
}

// raw v_exp_f32 (scores are range-bounded; skip ocml denormal guards)
__device__ __forceinline__ float fexp2(float x) {
#if __has_builtin(__builtin_amdgcn_exp2f)
  return __builtin_amdgcn_exp2f(x);
#else
  float r;
  asm("v_exp_f32 %0, %1" : "=v"(r) : "v"(x));
  return r;
#endif
}

// permlane swaps, hardened: builtin if available, else inline asm
__device__ __forceinline__ void plswap32(unsigned& a, unsigned& b) {
#if __has_builtin(__builtin_amdgcn_permlane32_swap)
  u32x2 r = __builtin_amdgcn_permlane32_swap(a, b, false, false);
  a = r.x; b = r.y;
#else
  asm volatile("v_permlane32_swap_b32 %0, %1" : "+v"(a), "+v"(b));
#endif
}
__device__ __forceinline__ void plswap16(unsigned& a, unsigned& b) {
#if __has_builtin(__builtin_amdgcn_permlane16_swap)
  u32x2 r = __builtin_amdgcn_permlane16_swap(a, b, false, false);
  a = r.x; b = r.y;
#else
  asm volatile("v_permlane16_swap_b32 %0, %1" : "+v"(a), "+v"(b));
#endif
}

// async global->LDS, 16B per lane; LDS dst = wave-uniform base + lane*16
typedef __attribute__((address_space(1))) const unsigned int g_u32;
typedef __attribute__((address_space(3))) unsigned int l_u32;
__device__ __forceinline__ void gload16(const void* g, void* l) {
  __builtin_amdgcn_global_load_lds((g_u32*)g, (l_u32*)l, 16, 0, 0);
}

// ---------------------------------------------------------------------------
// fp32 -> bf16 converters
// ---------------------------------------------------------------------------
__global__ __launch_bounds__(256) void cvt_x_k(const float* __restrict__ src,
                                               short* __restrict__ dst) {
  int i = (blockIdx.x * 256 + threadIdx.x) * 4;
  float4 v = *(const float4*)(src + i);
  s16x4 o = {f2bf(v.x), f2bf(v.y), f2bf(v.z), f2bf(v.w)};
  *(s16x4*)(dst + i) = o;
}

// w1 (Wq) is pre-scaled by C1 = 0.125*log2(e) so attn can exp2 scores directly
__global__ __launch_bounds__(256) void cvt6_k(const float* w0, const float* w1,
                                              const float* w2, const float* w3,
                                              const float* w4, const float* w5,
                                              short* __restrict__ dst) {
  int i = (blockIdx.x * 256 + threadIdx.x) * 4;
  int m = i / WSZ;
  int off = i - m * WSZ;
  const float* s = m == 0 ? w0 : m == 1 ? w1 : m == 2 ? w2 : m == 3 ? w3 : m == 4 ? w4 : w5;
  float sc = (m == 1) ? 0.1803368802f : 1.0f;
  float4 v = *(const float4*)(s + off);
  s16x4 o = {f2bf(v.x * sc), f2bf(v.y * sc), f2bf(v.z * sc), f2bf(v.w * sc)};
  *(s16x4*)(dst + i) = o;
}

// ---------------------------------------------------------------------------
// depthwise conv1d k=3 pad=1 over seq; vectorized x4, 192 thr (H/4=192)
// ---------------------------------------------------------------------------
__global__ __launch_bounds__(192) void dwconv_k(const float* __restrict__ prev,
                                                const float* __restrict__ w3,
                                                const float* __restrict__ bias,
                                                short* __restrict__ out) {
  int row = blockIdx.x;
  int s = row & (S_ - 1);
  int h = threadIdx.x * 4;
  size_t base = (size_t)row * H_ + h;
  float4 c = *(const float4*)(prev + base);
  float4 wa = *(const float4*)(w3 + h * 3);
  float4 wb = *(const float4*)(w3 + h * 3 + 4);
  float4 wc = *(const float4*)(w3 + h * 3 + 8);
  float4 bi = *(const float4*)(bias + h);
  float4 acc;
  acc.x = bi.x + c.x * wa.y;
  acc.y = bi.y + c.y * wb.x;
  acc.z = bi.z + c.z * wb.w;
  acc.w = bi.w + c.w * wc.z;
  if (s > 0) {
    float4 l = *(const float4*)(prev + base - H_);
    acc.x += l.x * wa.x; acc.y += l.y * wa.w; acc.z += l.z * wb.z; acc.w += l.w * wc.y;
  }
  if (s < S_ - 1) {
    float4 r = *(const float4*)(prev + base + H_);
    acc.x += r.x * wa.z; acc.y += r.y * wb.y; acc.z += r.z * wc.x; acc.w += r.w * wc.w;
  }
  s16x4 o = {f2bf(acc.x), f2bf(acc.y), f2bf(acc.z), f2bf(acc.w)};
  *(s16x4*)(out + base) = o;
}

// ---------------------------------------------------------------------------
// Grouped GEMM (QKV): 128x128 tiles, BK=64. 1D grid, XCD-swizzled.
// v3: 2-deep A-prefetch (triple-buffered A, double-buffered W) with counted
// vmcnt (T4): per iter [vmcnt(4); s_barrier; issue W(t+1), A(t+2); MFMA].
// Queue sim: at iter t the wait drains {A(t), W(t)}, keeps A(t+1) in flight.
// A (HBM-latency stream) gets 2 K-steps of cover; W is L2-hot (1 step ok).
// LDS 80 KB -> 2 blocks/CU.
// ---------------------------------------------------------------------------
struct GemmJob {
  const short* A; const short* W; const float* bias; short* C; int act; int tout;
  float bscale;
};

__global__ __launch_bounds__(256, 2) void gemm_bf2(GemmJob j0, GemmJob j1, GemmJob j2) {
  int d = blockIdx.x;
  int z = d / 384, r5 = d - z * 384;
  GemmJob j = z == 0 ? j0 : (z == 1 ? j1 : j2);
  int xcd = r5 & 7, s5 = r5 >> 3;          // s5 in [0,48)
  int nx = s5 % 6, ny = xcd + 8 * (s5 / 6);  // ny in [0,64)
  __shared__ short As[3][128 * 64];  // 3 x 16 KB
  __shared__ short Ws[2][128 * 64];  // 2 x 16 KB
  int tid = threadIdx.x, lane = tid & 63, w = tid >> 6;
  int wr = w >> 1, wc = w & 1, lm = lane & 15, lq = lane >> 4;
  int lm7 = lm & 15 & 7;
  int rb8 = (lq ^ lm7) << 3, rb8x = rb8 ^ 32;
  int m0 = ny * 128, n0 = nx * 128;
  int srow = lane >> 3;
  int jl = ((lane & 7) ^ srow) * 8;   // pre-swizzled source slot
  const short* gA = j.A + (size_t)(m0 + w * 32 + srow) * H_ + jl;
  const short* gW = j.W + (size_t)(n0 + w * 32 + srow) * H_ + jl;
  int lbase = w * 2048;

  f32x4 acc[4][4];
#pragma unroll
  for (int i = 0; i < 4; ++i)
#pragma unroll
    for (int jj = 0; jj < 4; ++jj) acc[i][jj] = (f32x4){0.f, 0.f, 0.f, 0.f};

  // prologue, order matters for vmcnt drain: A0, W0, A1
#pragma unroll
  for (int c = 0; c < 4; ++c)
    gload16(gA + (size_t)(c * 8) * H_, &As[0][lbase + c * 512]);
#pragma unroll
  for (int c = 0; c < 4; ++c)
    gload16(gW + (size_t)(c * 8) * H_, &Ws[0][lbase + c * 512]);
#pragma unroll
  for (int c = 0; c < 4; ++c)
    gload16(gA + 64 + (size_t)(c * 8) * H_, &As[1][lbase + c * 512]);

  const int NST = H_ / 64;  // 12
  for (int t = 0; t < NST; ++t) {
    if (t < NST - 1) asm volatile("s_waitcnt vmcnt(4)" ::: "memory");
    else             asm volatile("s_waitcnt vmcnt(0)" ::: "memory");
    __builtin_amdgcn_s_barrier();
    __builtin_amdgcn_sched_barrier(0);
    if (t + 1 < NST) {
      int kt1 = (t + 1) * 64;
#pragma unroll
      for (int c = 0; c < 4; ++c)
        gload16(gW + kt1 + (size_t)(c * 8) * H_, &Ws[(t + 1) & 1][lbase + c * 512]);
    }
    if (t + 2 < NST) {
      int kt2 = (t + 2) * 64;
      int a2 = (t + 2) % 3;
#pragma unroll
      for (int c = 0; c < 4; ++c)
        gload16(gA + kt2 + (size_t)(c * 8) * H_, &As[a2][lbase + c * 512]);
    }
    const short* Aw = &As[t % 3][0];
    const short* Ww = &Ws[t & 1][0];
#pragma unroll
    for (int kk = 0; kk < 2; ++kk) {
      int ro = kk ? rb8x : rb8;
      bf16x8 af[4], wf[4];
#pragma unroll
      for (int i = 0; i < 4; ++i)
        af[i] = *(const bf16x8*)&Aw[(wr * 64 + i * 16 + lm) * 64 + ro];
#pragma unroll
      for (int jj = 0; jj < 4; ++jj)
        wf[jj] = *(const bf16x8*)&Ww[(wc * 64 + jj * 16 + lm) * 64 + ro];
#pragma unroll
      for (int i = 0; i < 4; ++i)
#pragma unroll
        for (int jj = 0; jj < 4; ++jj)
          acc[i][jj] = __builtin_amdgcn_mfma_f32_16x16x32_bf16(af[i], wf[jj], acc[i][jj], 0, 0, 0);
    }
  }

  if (!j.tout) {
#pragma unroll
    for (int jj = 0; jj < 4; ++jj) {
      int col = n0 + wc * 64 + jj * 16 + lm;
      float bn = j.bias[col] * j.bscale;
#pragma unroll
      for (int i = 0; i < 4; ++i) {
        int mrow = m0 + wr * 64 + i * 16 + lq * 4;
#pragma unroll
        for (int r = 0; r < 4; ++r) {
          float cv = acc[i][jj][r] + bn;
          if (j.act) cv = 0.5f * cv * (1.0f + erff(cv * 0.70710678118f));
          j.C[(size_t)(mrow + r) * H_ + col] = f2bf(cv);
        }
      }
    }
  } else {
    int b = m0 >> 11;
    int sb = (m0 & (S_ - 1)) + wr * 64;
#pragma unroll
    for (int jj = 0; jj < 4; ++jj) {
      int col = n0 + wc * 64 + jj * 16 + lm;
      float bn = j.bias[col] * j.bscale;
      short* cp = j.C + ((size_t)(b * H_ + col)) * S_;
#pragma unroll
      for (int i = 0; i < 4; ++i) {
        int s = sb + i * 16 + lq * 4;
        s16x4 pk = {f2bf(acc[i][jj][0] + bn), f2bf(acc[i][jj][1] + bn),
                    f2bf(acc[i][jj][2] + bn), f2bf(acc[i][jj][3] + bn)};
        *(s16x4*)(cp + s) = pk;
      }
    }
  }
}

// ---------------------------------------------------------------------------
// Single GEMM, 128x64 tile: pw/o/post projections. 1D grid, XCD-swizzled.
// dbuf + swizzle staging; launch_bounds(256,3) matches real occupancy
// (grid 768 = 3 blocks/CU) -> VGPR cap 168, lets compiler hoist addresses.
// ---------------------------------------------------------------------------
__global__ __launch_bounds__(256, 3) void gemm_n64(const short* __restrict__ A,
                                                   const short* __restrict__ W,
                                                   const float* __restrict__ bias,
                                                   short* __restrict__ C, int act) {
  int d = blockIdx.x;
  int xcd = d & 7, s5 = d >> 3;            // s5 in [0,96)
  int nx = s5 % 12, ny = xcd + 8 * (s5 / 12);  // ny in [0,64)
  __shared__ short As[2][128 * 64];  // 2 x 16 KB
  __shared__ short Ws[2][64 * 64];   // 2 x 8 KB
  int tid = threadIdx.x, lane = tid & 63, w = tid >> 6;
  int wm = w >> 1, wn = w & 1, lm = lane & 15, lq = lane >> 4;
  int lm7 = lm & 7;
  int rb8 = (lq ^ lm7) << 3, rb8x = rb8 ^ 32;
  int m0 = ny * 128, n0 = nx * 64;
  int srow = lane >> 3;
  int jl = ((lane & 7) ^ srow) * 8;
  const short* gA = A + (size_t)(m0 + w * 32 + srow) * H_ + jl;
  const short* gW = W + (size_t)(n0 + w * 16 + srow) * H_ + jl;
  int lbaseA = w * 2048;  // 32 rows x 64
  int lbaseW = w * 1024;  // 16 rows x 64

  f32x4 acc[4][2];
#pragma unroll
  for (int i = 0; i < 4; ++i)
#pragma unroll
    for (int jj = 0; jj < 2; ++jj) acc[i][jj] = (f32x4){0.f, 0.f, 0.f, 0.f};

  // prologue: K-step 0 -> buf 0
#pragma unroll
  for (int c = 0; c < 4; ++c)
    gload16(gA + (size_t)(c * 8) * H_, &As[0][lbaseA + c * 512]);
#pragma unroll
  for (int c = 0; c < 2; ++c)
    gload16(gW + (size_t)(c * 8) * H_, &Ws[0][lbaseW + c * 512]);

  for (int kt = 0, pb = 0; kt < H_; kt += 64, pb ^= 1) {
    __syncthreads();
    if (kt + 64 < H_) {
#pragma unroll
      for (int c = 0; c < 4; ++c)
        gload16(gA + kt + 64 + (size_t)(c * 8) * H_, &As[pb ^ 1][lbaseA + c * 512]);
#pragma unroll
      for (int c = 0; c < 2; ++c)
        gload16(gW + kt + 64 + (size_t)(c * 8) * H_, &Ws[pb ^ 1][lbaseW + c * 512]);
    }
    const short* Aw = &As[pb][0];
    const short* Ww = &Ws[pb][0];
#pragma unroll
    for (int kk = 0; kk < 2; ++kk) {
      int ro = kk ? rb8x : rb8;
      bf16x8 af[4], wf[2];
#pragma unroll
      for (int i = 0; i < 4; ++i)
        af[i] = *(const bf16x8*)&Aw[(wm * 64 + i * 16 + lm) * 64 + ro];
#pragma unroll
      for (int jj = 0; jj < 2; ++jj)
        wf[jj] = *(const bf16x8*)&Ww[(wn * 32 + jj * 16 + lm) * 64 + ro];
#pragma unroll
      for (int i = 0; i < 4; ++i)
#pragma unroll
        for (int jj = 0; jj < 2; ++jj)
          acc[i][jj] = __builtin_amdgcn_mfma_f32_16x16x32_bf16(af[i], wf[jj], acc[i][jj], 0, 0, 0);
    }
  }

#pragma unroll
  for (int jj = 0; jj < 2; ++jj) {
    int col = n0 + wn * 32 + jj * 16 + lm;
    float bn = bias[col];
#pragma unroll
    for (int i = 0; i < 4; ++i) {
      int mrow = m0 + wm * 64 + i * 16 + lq * 4;
#pragma unroll
      for (int r = 0; r < 4; ++r) {
        float cv = acc[i][jj][r] + bn;
        if (act) cv = 0.5f * cv * (1.0f + erff(cv * 0.70710678118f));
        C[(size_t)(mrow + r) * H_ + col] = f2bf(cv);
      }
    }
  }
}

// ---------------------------------------------------------------------------
// LayerNorm over last dim (H=768), bf16 in -> bf16 out
// ---------------------------------------------------------------------------
__global__ __launch_bounds__(256) void ln_bf(const short* __restrict__ X,
                                             short* __restrict__ Y,
                                             const float* __restrict__ g,
                                             const float* __restrict__ bb) {
  int row = blockIdx.x;
  size_t base = (size_t)row * H_;
  int h0 = threadIdx.x, h1 = h0 + 256, h2 = h0 + 512;
  float x0 = bf2f(X[base + h0]), x1 = bf2f(X[base + h1]), x2 = bf2f(X[base + h2]);
  float s = x0 + x1 + x2;
  float s2 = x0 * x0 + x1 * x1 + x2 * x2;
  for (int off = 32; off > 0; off >>= 1) {
    s += __shfl_down(s, off);
    s2 += __shfl_down(s2, off);
  }
  __shared__ float sa[4], sq[4], st[2];
  int wid = threadIdx.x >> 6, lane = threadIdx.x & 63;
  if (lane == 0) { sa[wid] = s; sq[wid] = s2; }
  __syncthreads();
  if (threadIdx.x == 0) {
    float ts = sa[0] + sa[1] + sa[2] + sa[3];
    float ts2 = sq[0] + sq[1] + sq[2] + sq[3];
    float mean = ts * (1.0f / H_);
    float var = ts2 * (1.0f / H_) - mean * mean;
    st[0] = mean;
    st[1] = rsqrtf(var + 1e-5f);
  }
  __syncthreads();
  float mean = st[0], rstd = st[1];
  Y[base + h0] = f2bf((x0 - mean) * rstd * g[h0] + bb[h0]);
  Y[base + h1] = f2bf((x1 - mean) * rstd * g[h1] + bb[h1]);
  Y[base + h2] = f2bf((x2 - mean) * rstd * g[h2] + bb[h2]);
}

// ---------------------------------------------------------------------------
// MFMA flash attention v8b: structure unchanged from R6; launch_bounds(256,3)
// matches real occupancy (3 blocks/CU) -> VGPR cap 168 (was squeezed to 72),
// freeing the compiler to hoist the 16 LDS fragment addresses + staging
// addresses out of the tile loop.
// ---------------------------------------------------------------------------
__global__ __launch_bounds__(256, 3) void attn8_k(const short* __restrict__ qb,
                                                  const short* __restrict__ kb,
                                                  const short* __restrict__ vtb,
                                                  short* __restrict__ aob) {
  __shared__ short Ks[2][64 * 64];     // [sk][d] swizzled, 2 x 8 KB
  __shared__ short Vt[2][64 * 64];     // [d][sk] swizzled, 2 x 8 KB
  int tid = threadIdx.x, lane = tid & 63, w = tid >> 6;  // w 0..3
  int lm = lane & 15, lq = lane >> 4;
  int lm7 = lm & 7;
  int dd = blockIdx.x;
  int xcd = dd & 7, slot = dd >> 3;          // slot in [0,96)
  int g = xcd + 8 * (slot >> 4);             // g in [0,48)
  int qx = slot & 15;
  int b = g / NH_, n = g - b * NH_;
  int q0 = qx * 128;
  int hoff = n * HD_;

  int rb8 = (lq ^ lm7) << 3;
  int rb8x = rb8 ^ 32;

  bf16x8 qf[2][2];
#pragma unroll
  for (int qg = 0; qg < 2; ++qg) {
    const short* qrow = qb + ((size_t)(b * S_ + q0 + w * 32 + qg * 16 + lm)) * H_ + hoff;
    qf[qg][0] = *(const bf16x8*)(qrow + lq * 8);
    qf[qg][1] = *(const bf16x8*)(qrow + 32 + lq * 8);
  }

  bf16x8 onef = {0x3F80, 0x3F80, 0x3F80, 0x3F80, 0x3F80, 0x3F80, 0x3F80, 0x3F80};
  f32x4 ls[2];
  ls[0] = (f32x4){0.f, 0.f, 0.f, 0.f};
  ls[1] = (f32x4){0.f, 0.f, 0.f, 0.f};

  f32x4 o[4][2];
#pragma unroll
  for (int i = 0; i < 4; ++i)
#pragma unroll
    for (int qg = 0; qg < 2; ++qg) o[i][qg] = (f32x4){0.f, 0.f, 0.f, 0.f};

  int jl = ((lane & 7) ^ (lane >> 3)) * 8;
  int rr = w * 16 + (lane >> 3);
  const short* kgl = kb + ((size_t)(b * S_ + rr)) * H_ + hoff + jl;
  const short* vgl = vtb + ((size_t)(b * H_ + hoff + rr)) * S_ + jl;
  int lbase = w * 1024;

#pragma unroll
  for (int c = 0; c < 2; ++c) {
    gload16(kgl + (size_t)(c * 8) * H_, &Ks[0][lbase + c * 512]);
    gload16(vgl + (size_t)(c * 8) * S_, &Vt[0][lbase + c * 512]);
  }

  for (int kt = 0, pb = 0; kt < S_; kt += 64, pb ^= 1) {
    __syncthreads();
    if (kt + 64 < S_) {
#pragma unroll
      for (int c = 0; c < 2; ++c) {
        gload16(kgl + (size_t)(kt + 64 + c * 8) * H_, &Ks[pb ^ 1][lbase + c * 512]);
        gload16(vgl + (size_t)(c * 8) * S_ + (kt + 64), &Vt[pb ^ 1][lbase + c * 512]);
      }
    }
    const short* Kw = &Ks[pb][0];
    const short* Vw = &Vt[pb][0];

    f32x4 st[4][2];
    __builtin_amdgcn_s_setprio(1);
#pragma unroll
    for (int ni = 0; ni < 4; ++ni) {
      int krow = (ni * 16 + lm) * 64;
      bf16x8 ka0 = *(const bf16x8*)&Kw[krow + rb8];
      bf16x8 ka1 = *(const bf16x8*)&Kw[krow + rb8x];
#pragma unroll
      for (int qg = 0; qg < 2; ++qg) {
        f32x4 z = (f32x4){0.f, 0.f, 0.f, 0.f};
        z = __builtin_amdgcn_mfma_f32_16x16x32_bf16(ka0, qf[qg][0], z, 0, 0, 0);
        st[ni][qg] = __builtin_amdgcn_mfma_f32_16x16x32_bf16(ka1, qf[qg][1], z, 0, 0, 0);
      }
    }
    __builtin_amdgcn_s_setprio(0);

    bf16x8 pf[2][2];
#pragma unroll
    for (int qg = 0; qg < 2; ++qg) {
      unsigned pw0, pw1, pw2, pw3, pw4, pw5, pw6, pw7;
      {
        float p0 = fexp2(st[0][qg][0]), p1 = fexp2(st[0][qg][1]);
        float p2 = fexp2(st[0][qg][2]), p3 = fexp2(st[0][qg][3]);
        pw0 = bfpack(p0, p1); pw1 = bfpack(p2, p3);
      }
      {
        float p0 = fexp2(st[1][qg][0]), p1 = fexp2(st[1][qg][1]);
        float p2 = fexp2(st[1][qg][2]), p3 = fexp2(st[1][qg][3]);
        pw2 = bfpack(p0, p1); pw3 = bfpack(p2, p3);
      }
      {
        float p0 = fexp2(st[2][qg][0]), p1 = fexp2(st[2][qg][1]);
        float p2 = fexp2(st[2][qg][2]), p3 = fexp2(st[2][qg][3]);
        pw4 = bfpack(p0, p1); pw5 = bfpack(p2, p3);
      }
      {
        float p0 = fexp2(st[3][qg][0]), p1 = fexp2(st[3][qg][1]);
        float p2 = fexp2(st[3][qg][2]), p3 = fexp2(st[3][qg][3]);
        pw6 = bfpack(p0, p1); pw7 = bfpack(p2, p3);
      }
      plswap32(pw0, pw2); plswap16(pw0, pw2);
      plswap32(pw1, pw3); plswap16(pw1, pw3);
      plswap32(pw4, pw6); plswap16(pw4, pw6);
      plswap32(pw5, pw7); plswap16(pw5, pw7);
      union { u32x4 u; bf16x8 v; } c0u, c1u;
      c0u.u = (u32x4){pw0, pw1, pw2, pw3};
      c1u.u = (u32x4){pw4, pw5, pw6, pw7};
      pf[qg][0] = c0u.v;
      pf[qg][1] = c1u.v;
    }

    __builtin_amdgcn_s_setprio(1);
#pragma unroll
    for (int qg = 0; qg < 2; ++qg) {
      ls[qg] = __builtin_amdgcn_mfma_f32_16x16x32_bf16(onef, pf[qg][0], ls[qg], 0, 0, 0);
      ls[qg] = __builtin_amdgcn_mfma_f32_16x16x32_bf16(onef, pf[qg][1], ls[qg], 0, 0, 0);
    }
#pragma unroll
    for (int nd = 0; nd < 4; ++nd) {
      int vrow = (nd * 16 + lm) * 64;
      bf16x8 va0 = *(const bf16x8*)&Vw[vrow + rb8];
      bf16x8 va1 = *(const bf16x8*)&Vw[vrow + rb8x];
#pragma unroll
      for (int qg = 0; qg < 2; ++qg) {
        o[nd][qg] = __builtin_amdgcn_mfma_f32_16x16x32_bf16(va0, pf[qg][0], o[nd][qg], 0, 0, 0);
        o[nd][qg] = __builtin_amdgcn_mfma_f32_16x16x32_bf16(va1, pf[qg][1], o[nd][qg], 0, 0, 0);
      }
    }
    __builtin_amdgcn_s_setprio(0);
  }

#pragma unroll
  for (int qg = 0; qg < 2; ++qg) {
    float inv = 1.0f / ls[qg][0];
    short* orow = aob + ((size_t)(b * S_ + q0 + w * 32 + qg * 16 + lm)) * H_ + hoff;
#pragma unroll
    for (int nd = 0; nd < 4; ++nd) {
      s16x4 pk = {f2bf(o[nd][qg][0] * inv), f2bf(o[nd][qg][1] * inv),
                  f2bf(o[nd][qg][2] * inv), f2bf(o[nd][qg][3] * inv)};
      *(s16x4*)(orow + nd * 16 + lq * 4) = pk;
    }
  }
}

// ---------------------------------------------------------------------------
// gate + masked residual + aux partials. 192 thr, x4 vectorized.
// ---------------------------------------------------------------------------
__global__ __launch_bounds__(192) void gate_out_k(const float* __restrict__ x,
                                                  const short* __restrict__ br,
                                                  const short* __restrict__ inj,
                                                  const int* __restrict__ mask,
                                                  const float* __restrict__ Wg,
                                                  const float* __restrict__ bg,
                                                  float* __restrict__ out,
                                                  float* __restrict__ paux) {
  int row = blockIdx.x;
  int b = row >> 11;
  size_t base = (size_t)row * H_;
  int h = threadIdx.x * 4;
  float4 xv = *(const float4*)(x + base + h);
  s16x4 brv = *(const s16x4*)(br + base + h);
  s16x4 inv = *(const s16x4*)(inj + base + h);
  float4 wg0 = *(const float4*)(Wg + h);
  float4 wg1 = *(const float4*)(Wg + H_ + h);
  float b0 = bf2f(brv.x), b1 = bf2f(brv.y), b2 = bf2f(brv.z), b3 = bf2f(brv.w);
  float dot = xv.x * wg0.x + xv.y * wg0.y + xv.z * wg0.z + xv.w * wg0.w
            + b0 * wg1.x + b1 * wg1.y + b2 * wg1.z + b3 * wg1.w;
  float d0 = b0 - xv.x, d1 = b1 - xv.y, d2 = b2 - xv.z, d3 = b3 - xv.w;
  float aux = d0 * d0 + d1 * d1 + d2 * d2 + d3 * d3;
  for (int off = 32; off > 0; off >>= 1) {
    dot += __shfl_down(dot, off);
    aux += __shfl_down(aux, off);
  }
  __shared__ float sd[3], sx[3], gsh[2];
  int wid = threadIdx.x >> 6, lane = threadIdx.x & 63;
  if (lane == 0) { sd[wid] = dot; sx[wid] = aux; }
  __syncthreads();
  if (threadIdx.x == 0) {
    float td = sd[0] + sd[1] + sd[2];
    float ta = sx[0] + sx[1] + sx[2];
    gsh[0] = 1.0f / (1.0f + expf(-(td + bg[0])));
    gsh[1] = ta;
  }
  __syncthreads();
  float mf = (mask[b] != 0) ? 1.0f : 0.0f;
  float gm = gsh[0] * mf;
  float v0 = bf2f(inv.x), v1 = bf2f(inv.y), v2 = bf2f(inv.z), v3 = bf2f(inv.w);
  float e0 = __expf(2.f * v0), e1 = __expf(2.f * v1), e2 = __expf(2.f * v2), e3 = __expf(2.f * v3);
  float4 ov;
  ov.x = xv.x + gm * ((e0 - 1.f) / (e0 + 1.f));
  ov.y = xv.y + gm * ((e1 - 1.f) / (e1 + 1.f));
  ov.z = xv.z + gm * ((e2 - 1.f) / (e2 + 1.f));
  ov.w = xv.w + gm * ((e3 - 1.f) / (e3 + 1.f));
  *(float4*)(out + base + h) = ov;
  if (threadIdx.x == 0) paux[row] = mf * gsh[1];
}

__global__ __launch_bounds__(256) void aux_reduce_k(const float* __restrict__ paux,
                                                    const int* __restrict__ mask,
                                                    float* __restrict__ outp) {
  float s = 0.f;
  for (int i = threadIdx.x; i < NROWS; i += 256) s += paux[i];
  for (int off = 32; off > 0; off >>= 1) s += __shfl_down(s, off);
  __shared__ float sw[4];
  int wid = threadIdx.x >> 6, lane = threadIdx.x & 63;
  if (lane == 0) sw[wid] = s;
  __syncthreads();
  if (threadIdx.x == 0) {
    float t = sw[0] + sw[1] + sw[2] + sw[3];
    int nm = (mask[0] != 0) + (mask[1] != 0) + (mask[2] != 0) + (mask[3] != 0);
    if (nm < 1) nm = 1;
    outp[0] = t / ((float)nm * (float)(S_ * H_));
  }
}

// ---------------------------------------------------------------------------
extern "C" void kernel_launch(void* const* d_in, const int* in_sizes, int n_in,
                              void* d_out, int out_size, void* d_ws, size_t ws_size,
                              hipStream_t stream) {
  const float* x     = (const float*)d_in[0];
  const float* prev  = (const float*)d_in[1];
  const int*   mask  = (const int*)d_in[2];
  const float* dw_w  = (const float*)d_in[3];
  const float* dw_b  = (const float*)d_in[4];
  const float* pw_w  = (const float*)d_in[5];
  const float* pw_b  = (const float*)d_in[6];
  const float* cn_g  = (const float*)d_in[7];
  const float* cn_b  = (const float*)d_in[8];
  const float* Wq    = (const float*)d_in[9];
  const float* bq    = (const float*)d_in[10];
  const float* Wk    = (const float*)d_in[11];
  const float* bk    = (const float*)d_in[12];
  const float* Wv    = (const float*)d_in[13];
  const float* bv    = (const float*)d_in[14];
  const float* Wo    = (const float*)d_in[15];
  const float* bo    = (const float*)d_in[16];
  const float* pn_g  = (const float*)d_in[17];
  const float* pn_b  = (const float*)d_in[18];
  const float* Wpost = (const float*)d_in[19];
  const float* bpost = (const float*)d_in[20];
  const float* Wg    = (const float*)d_in[21];
  const float* bg    = (const float*)d_in[22];
  float* out = (float*)d_out;

  short* B0 = (short*)d_ws;     // xb
  short* B1 = B0 + BSH;         // dwo -> qb
  short* B2 = B1 + BSH;         // gelu-out -> aob
  short* B3 = B2 + BSH;         // bridged (until gate)
  short* B4 = B3 + BSH;         // kb -> ao_proj -> pn
  short* B5 = B4 + BSH;         // vtb -> injb
  short* WW = B5 + BSH;         // 6 bf16 weights [pw,q,k,v,o,post]
  float* paux = (float*)(WW + 6 * WSZ);

  const float C1 = 0.1803368802f;  // 0.125 * log2(e), folded into Wq/bq

  GemmJob jq = {B0, WW + WSZ,     bq, B1, 0, 0, C1};
  GemmJob jk = {B3, WW + 2 * WSZ, bk, B4, 0, 0, 1.0f};
  GemmJob jv = {B3, WW + 3 * WSZ, bv, B5, 0, 1, 1.0f};

  cvt6_k<<<6 * WSZ / 1024, 256, 0, stream>>>(pw_w, Wq, Wk, Wv, Wo, Wpost, WW);
  cvt_x_k<<<BSH / 1024, 256, 0, stream>>>(x, B0);
  dwconv_k<<<NROWS, 192, 0, stream>>>(prev, dw_w, dw_b, B1);
  gemm_n64<<<768, 256, 0, stream>>>(B1, WW, pw_b, B2, 1);                  // pw + GELU
  ln_bf<<<NROWS, 256, 0, stream>>>(B2, B3, cn_g, cn_b);                    // bridged
  gemm_bf2<<<1152, 256, 0, stream>>>(jq, jk, jv);                          // Q,K,V grouped
  attn8_k<<<768, 256, 0, stream>>>(B1, B4, B5, B2);                        // -> aob
  gemm_n64<<<768, 256, 0, stream>>>(B2, WW + 4 * WSZ, bo, B4, 0);          // o-proj
  ln_bf<<<NROWS, 256, 0, stream>>>(B4, B4, pn_g, pn_b);                    // pn
  gemm_n64<<<768, 256, 0, stream>>>(B4, WW + 5 * WSZ, bpost, B5, 0);       // post
  gate_out_k<<<NROWS, 192, 0, stream>>>(x, B3, B5, mask, Wg, bg, out, paux);
  aux_reduce_k<<<1, 256, 0, stream>>>(paux, mask, out + BSH);
}

// Round 8
// 348.387 us; speedup vs baseline: 1.1232x; 1.0301x over previous
//
#include <hip/hip_runtime.h>
#include <math.h>

#define B_ 4
#define S_ 2048
#define H_ 768
#define NH_ 12
#define HD_ 64
#define BSH (B_ * S_ * H_)
#define NROWS (B_ * S_)
#define WSZ (H_ * H_)  // 589824

typedef __attribute__((ext_vector_type(8))) short bf16x8;
typedef __attribute__((ext_vector_type(4))) short s16x4;
typedef __attribute__((ext_vector_type(4))) float f32x4;
typedef __attribute__((ext_vector_type(2))) unsigned u32x2;
typedef __attribute__((ext_vector_type(4))) unsigned u32x4;

__device__ __forceinline__ short f2bf(float f) {
  union { float f; unsigned u; } x; x.f = f;
  unsigned r = x.u + 0x7FFF + ((x.u >> 16) & 1);
  return (short)(r >> 16);
}
__device__ __forceinline__ float bf2f(short s) {
  union { unsigned u; float f; } x;
  x.u = ((unsigned)(unsigned short)s) << 16;
  return x.f;
}
// pack 2 fp32 -> 2 bf16 (truncation) in one v_perm_b32
__device__ __forceinline__ unsigned bfpack(float lo, float hi) {
  union { float f; unsigned u; } a, b; a.f = lo; b.f = hi;
  return __builtin_amdgcn_perm(b.u, a.u, 0x07060302);
}

// raw v_exp_f32 (scores are range-bounded; skip ocml denormal guards)
__device__ __forceinline__ float fexp2(float x) {
#if __has_builtin(__builtin_amdgcn_exp2f)
  return __builtin_amdgcn_exp2f(x);
#else
  float r;
  asm("v_exp_f32 %0, %1" : "=v"(r) : "v"(x));
  return r;
#endif
}

// permlane swaps, hardened: builtin if available, else inline asm
__device__ __forceinline__ void plswap32(unsigned& a, unsigned& b) {
#if __has_builtin(__builtin_amdgcn_permlane32_swap)
  u32x2 r = __builtin_amdgcn_permlane32_swap(a, b, false, false);
  a = r.x; b = r.y;
#else
  asm volatile("v_permlane32_swap_b32 %0, %1" : "+v"(a), "+v"(b));
#endif
}
__device__ __forceinline__ void plswap16(unsigned& a, unsigned& b) {
#if __has_builtin(__builtin_amdgcn_permlane16_swap)
  u32x2 r = __builtin_amdgcn_permlane16_swap(a, b, false, false);
  a = r.x; b = r.y;
#else
  asm volatile("v_permlane16_swap_b32 %0, %1" : "+v"(a), "+v"(b));
#endif
}

// async global->LDS, 16B per lane; LDS dst = wave-uniform base + lane*16
typedef __attribute__((address_space(1))) const unsigned int g_u32;
typedef __attribute__((address_space(3))) unsigned int l_u32;
__device__ __forceinline__ void gload16(const void* g, void* l) {
  __builtin_amdgcn_global_load_lds((g_u32*)g, (l_u32*)l, 16, 0, 0);
}

// ---------------------------------------------------------------------------
// fp32 -> bf16 converters
// ---------------------------------------------------------------------------
__global__ __launch_bounds__(256) void cvt_x_k(const float* __restrict__ src,
                                               short* __restrict__ dst) {
  int i = (blockIdx.x * 256 + threadIdx.x) * 4;
  float4 v = *(const float4*)(src + i);
  s16x4 o = {f2bf(v.x), f2bf(v.y), f2bf(v.z), f2bf(v.w)};
  *(s16x4*)(dst + i) = o;
}

// w1 (Wq) is pre-scaled by C1 = 0.125*log2(e) so attn can exp2 scores directly
__global__ __launch_bounds__(256) void cvt6_k(const float* w0, const float* w1,
                                              const float* w2, const float* w3,
                                              const float* w4, const float* w5,
                                              short* __restrict__ dst) {
  int i = (blockIdx.x * 256 + threadIdx.x) * 4;
  int m = i / WSZ;
  int off = i - m * WSZ;
  const float* s = m == 0 ? w0 : m == 1 ? w1 : m == 2 ? w2 : m == 3 ? w3 : m == 4 ? w4 : w5;
  float sc = (m == 1) ? 0.1803368802f : 1.0f;
  float4 v = *(const float4*)(s + off);
  s16x4 o = {f2bf(v.x * sc), f2bf(v.y * sc), f2bf(v.z * sc), f2bf(v.w * sc)};
  *(s16x4*)(dst + i) = o;
}

// ---------------------------------------------------------------------------
// depthwise conv1d k=3 pad=1 over seq; vectorized x4, 192 thr (H/4=192)
// ---------------------------------------------------------------------------
__global__ __launch_bounds__(192) void dwconv_k(const float* __restrict__ prev,
                                                const float* __restrict__ w3,
                                                const float* __restrict__ bias,
                                                short* __restrict__ out) {
  int row = blockIdx.x;
  int s = row & (S_ - 1);
  int h = threadIdx.x * 4;
  size_t base = (size_t)row * H_ + h;
  float4 c = *(const float4*)(prev + base);
  float4 wa = *(const float4*)(w3 + h * 3);
  float4 wb = *(const float4*)(w3 + h * 3 + 4);
  float4 wc = *(const float4*)(w3 + h * 3 + 8);
  float4 bi = *(const float4*)(bias + h);
  float4 acc;
  acc.x = bi.x + c.x * wa.y;
  acc.y = bi.y + c.y * wb.x;
  acc.z = bi.z + c.z * wb.w;
  acc.w = bi.w + c.w * wc.z;
  if (s > 0) {
    float4 l = *(const float4*)(prev + base - H_);
    acc.x += l.x * wa.x; acc.y += l.y * wa.w; acc.z += l.z * wb.z; acc.w += l.w * wc.y;
  }
  if (s < S_ - 1) {
    float4 r = *(const float4*)(prev + base + H_);
    acc.x += r.x * wa.z; acc.y += r.y * wb.y; acc.z += r.z * wc.x; acc.w += r.w * wc.w;
  }
  s16x4 o = {f2bf(acc.x), f2bf(acc.y), f2bf(acc.z), f2bf(acc.w)};
  *(s16x4*)(out + base) = o;
}

// ---------------------------------------------------------------------------
// Grouped GEMM (QKV): 128x128 tiles, BK=64. 1D grid, XCD-swizzled.
// v3: 2-deep A-prefetch (triple-buffered A, double-buffered W) with counted
// vmcnt (T4). LDS 80 KB -> 2 blocks/CU.
// ---------------------------------------------------------------------------
struct GemmJob {
  const short* A; const short* W; const float* bias; short* C; int act; int tout;
  float bscale;
};

__global__ __launch_bounds__(256, 2) void gemm_bf2(GemmJob j0, GemmJob j1, GemmJob j2) {
  int d = blockIdx.x;
  int z = d / 384, r5 = d - z * 384;
  GemmJob j = z == 0 ? j0 : (z == 1 ? j1 : j2);
  int xcd = r5 & 7, s5 = r5 >> 3;          // s5 in [0,48)
  int nx = s5 % 6, ny = xcd + 8 * (s5 / 6);  // ny in [0,64)
  __shared__ short As[3][128 * 64];  // 3 x 16 KB
  __shared__ short Ws[2][128 * 64];  // 2 x 16 KB
  int tid = threadIdx.x, lane = tid & 63, w = tid >> 6;
  int wr = w >> 1, wc = w & 1, lm = lane & 15, lq = lane >> 4;
  int lm7 = lm & 7;
  int rb8 = (lq ^ lm7) << 3, rb8x = rb8 ^ 32;
  int m0 = ny * 128, n0 = nx * 128;
  int srow = lane >> 3;
  int jl = ((lane & 7) ^ srow) * 8;   // pre-swizzled source slot
  const short* gA = j.A + (size_t)(m0 + w * 32 + srow) * H_ + jl;
  const short* gW = j.W + (size_t)(n0 + w * 32 + srow) * H_ + jl;
  int lbase = w * 2048;

  f32x4 acc[4][4];
#pragma unroll
  for (int i = 0; i < 4; ++i)
#pragma unroll
    for (int jj = 0; jj < 4; ++jj) acc[i][jj] = (f32x4){0.f, 0.f, 0.f, 0.f};

  // prologue, order matters for vmcnt drain: A0, W0, A1
#pragma unroll
  for (int c = 0; c < 4; ++c)
    gload16(gA + (size_t)(c * 8) * H_, &As[0][lbase + c * 512]);
#pragma unroll
  for (int c = 0; c < 4; ++c)
    gload16(gW + (size_t)(c * 8) * H_, &Ws[0][lbase + c * 512]);
#pragma unroll
  for (int c = 0; c < 4; ++c)
    gload16(gA + 64 + (size_t)(c * 8) * H_, &As[1][lbase + c * 512]);

  const int NST = H_ / 64;  // 12
  for (int t = 0; t < NST; ++t) {
    if (t < NST - 1) asm volatile("s_waitcnt vmcnt(4)" ::: "memory");
    else             asm volatile("s_waitcnt vmcnt(0)" ::: "memory");
    __builtin_amdgcn_s_barrier();
    __builtin_amdgcn_sched_barrier(0);
    if (t + 1 < NST) {
      int kt1 = (t + 1) * 64;
#pragma unroll
      for (int c = 0; c < 4; ++c)
        gload16(gW + kt1 + (size_t)(c * 8) * H_, &Ws[(t + 1) & 1][lbase + c * 512]);
    }
    if (t + 2 < NST) {
      int kt2 = (t + 2) * 64;
      int a2 = (t + 2) % 3;
#pragma unroll
      for (int c = 0; c < 4; ++c)
        gload16(gA + kt2 + (size_t)(c * 8) * H_, &As[a2][lbase + c * 512]);
    }
    const short* Aw = &As[t % 3][0];
    const short* Ww = &Ws[t & 1][0];
#pragma unroll
    for (int kk = 0; kk < 2; ++kk) {
      int ro = kk ? rb8x : rb8;
      bf16x8 af[4], wf[4];
#pragma unroll
      for (int i = 0; i < 4; ++i)
        af[i] = *(const bf16x8*)&Aw[(wr * 64 + i * 16 + lm) * 64 + ro];
#pragma unroll
      for (int jj = 0; jj < 4; ++jj)
        wf[jj] = *(const bf16x8*)&Ww[(wc * 64 + jj * 16 + lm) * 64 + ro];
#pragma unroll
      for (int i = 0; i < 4; ++i)
#pragma unroll
        for (int jj = 0; jj < 4; ++jj)
          acc[i][jj] = __builtin_amdgcn_mfma_f32_16x16x32_bf16(af[i], wf[jj], acc[i][jj], 0, 0, 0);
    }
  }

  if (!j.tout) {
#pragma unroll
    for (int jj = 0; jj < 4; ++jj) {
      int col = n0 + wc * 64 + jj * 16 + lm;
      float bn = j.bias[col] * j.bscale;
#pragma unroll
      for (int i = 0; i < 4; ++i) {
        int mrow = m0 + wr * 64 + i * 16 + lq * 4;
#pragma unroll
        for (int r = 0; r < 4; ++r) {
          float cv = acc[i][jj][r] + bn;
          if (j.act) cv = 0.5f * cv * (1.0f + erff(cv * 0.70710678118f));
          j.C[(size_t)(mrow + r) * H_ + col] = f2bf(cv);
        }
      }
    }
  } else {
    int b = m0 >> 11;
    int sb = (m0 & (S_ - 1)) + wr * 64;
#pragma unroll
    for (int jj = 0; jj < 4; ++jj) {
      int col = n0 + wc * 64 + jj * 16 + lm;
      float bn = j.bias[col] * j.bscale;
      short* cp = j.C + ((size_t)(b * H_ + col)) * S_;
#pragma unroll
      for (int i = 0; i < 4; ++i) {
        int s = sb + i * 16 + lq * 4;
        s16x4 pk = {f2bf(acc[i][jj][0] + bn), f2bf(acc[i][jj][1] + bn),
                    f2bf(acc[i][jj][2] + bn), f2bf(acc[i][jj][3] + bn)};
        *(s16x4*)(cp + s) = pk;
      }
    }
  }
}

// ---------------------------------------------------------------------------
// Single GEMM, 128x64 tile: pw/o/post projections. 1D grid, XCD-swizzled.
// dbuf + swizzle staging; launch_bounds(256,3) matches real occupancy.
// ---------------------------------------------------------------------------
__global__ __launch_bounds__(256, 3) void gemm_n64(const short* __restrict__ A,
                                                   const short* __restrict__ W,
                                                   const float* __restrict__ bias,
                                                   short* __restrict__ C, int act) {
  int d = blockIdx.x;
  int xcd = d & 7, s5 = d >> 3;            // s5 in [0,96)
  int nx = s5 % 12, ny = xcd + 8 * (s5 / 12);  // ny in [0,64)
  __shared__ short As[2][128 * 64];  // 2 x 16 KB
  __shared__ short Ws[2][64 * 64];   // 2 x 8 KB
  int tid = threadIdx.x, lane = tid & 63, w = tid >> 6;
  int wm = w >> 1, wn = w & 1, lm = lane & 15, lq = lane >> 4;
  int lm7 = lm & 7;
  int rb8 = (lq ^ lm7) << 3, rb8x = rb8 ^ 32;
  int m0 = ny * 128, n0 = nx * 64;
  int srow = lane >> 3;
  int jl = ((lane & 7) ^ srow) * 8;
  const short* gA = A + (size_t)(m0 + w * 32 + srow) * H_ + jl;
  const short* gW = W + (size_t)(n0 + w * 16 + srow) * H_ + jl;
  int lbaseA = w * 2048;  // 32 rows x 64
  int lbaseW = w * 1024;  // 16 rows x 64

  f32x4 acc[4][2];
#pragma unroll
  for (int i = 0; i < 4; ++i)
#pragma unroll
    for (int jj = 0; jj < 2; ++jj) acc[i][jj] = (f32x4){0.f, 0.f, 0.f, 0.f};

  // prologue: K-step 0 -> buf 0
#pragma unroll
  for (int c = 0; c < 4; ++c)
    gload16(gA + (size_t)(c * 8) * H_, &As[0][lbaseA + c * 512]);
#pragma unroll
  for (int c = 0; c < 2; ++c)
    gload16(gW + (size_t)(c * 8) * H_, &Ws[0][lbaseW + c * 512]);

  for (int kt = 0, pb = 0; kt < H_; kt += 64, pb ^= 1) {
    __syncthreads();
    if (kt + 64 < H_) {
#pragma unroll
      for (int c = 0; c < 4; ++c)
        gload16(gA + kt + 64 + (size_t)(c * 8) * H_, &As[pb ^ 1][lbaseA + c * 512]);
#pragma unroll
      for (int c = 0; c < 2; ++c)
        gload16(gW + kt + 64 + (size_t)(c * 8) * H_, &Ws[pb ^ 1][lbaseW + c * 512]);
    }
    const short* Aw = &As[pb][0];
    const short* Ww = &Ws[pb][0];
#pragma unroll
    for (int kk = 0; kk < 2; ++kk) {
      int ro = kk ? rb8x : rb8;
      bf16x8 af[4], wf[2];
#pragma unroll
      for (int i = 0; i < 4; ++i)
        af[i] = *(const bf16x8*)&Aw[(wm * 64 + i * 16 + lm) * 64 + ro];
#pragma unroll
      for (int jj = 0; jj < 2; ++jj)
        wf[jj] = *(const bf16x8*)&Ww[(wn * 32 + jj * 16 + lm) * 64 + ro];
#pragma unroll
      for (int i = 0; i < 4; ++i)
#pragma unroll
        for (int jj = 0; jj < 2; ++jj)
          acc[i][jj] = __builtin_amdgcn_mfma_f32_16x16x32_bf16(af[i], wf[jj], acc[i][jj], 0, 0, 0);
    }
  }

#pragma unroll
  for (int jj = 0; jj < 2; ++jj) {
    int col = n0 + wn * 32 + jj * 16 + lm;
    float bn = bias[col];
#pragma unroll
    for (int i = 0; i < 4; ++i) {
      int mrow = m0 + wm * 64 + i * 16 + lq * 4;
#pragma unroll
      for (int r = 0; r < 4; ++r) {
        float cv = acc[i][jj][r] + bn;
        if (act) cv = 0.5f * cv * (1.0f + erff(cv * 0.70710678118f));
        C[(size_t)(mrow + r) * H_ + col] = f2bf(cv);
      }
    }
  }
}

// ---------------------------------------------------------------------------
// LayerNorm over last dim (H=768), bf16 in -> bf16 out
// ---------------------------------------------------------------------------
__global__ __launch_bounds__(256) void ln_bf(const short* __restrict__ X,
                                             short* __restrict__ Y,
                                             const float* __restrict__ g,
                                             const float* __restrict__ bb) {
  int row = blockIdx.x;
  size_t base = (size_t)row * H_;
  int h0 = threadIdx.x, h1 = h0 + 256, h2 = h0 + 512;
  float x0 = bf2f(X[base + h0]), x1 = bf2f(X[base + h1]), x2 = bf2f(X[base + h2]);
  float s = x0 + x1 + x2;
  float s2 = x0 * x0 + x1 * x1 + x2 * x2;
  for (int off = 32; off > 0; off >>= 1) {
    s += __shfl_down(s, off);
    s2 += __shfl_down(s2, off);
  }
  __shared__ float sa[4], sq[4], st[2];
  int wid = threadIdx.x >> 6, lane = threadIdx.x & 63;
  if (lane == 0) { sa[wid] = s; sq[wid] = s2; }
  __syncthreads();
  if (threadIdx.x == 0) {
    float ts = sa[0] + sa[1] + sa[2] + sa[3];
    float ts2 = sq[0] + sq[1] + sq[2] + sq[3];
    float mean = ts * (1.0f / H_);
    float var = ts2 * (1.0f / H_) - mean * mean;
    st[0] = mean;
    st[1] = rsqrtf(var + 1e-5f);
  }
  __syncthreads();
  float mean = st[0], rstd = st[1];
  Y[base + h0] = f2bf((x0 - mean) * rstd * g[h0] + bb[h0]);
  Y[base + h1] = f2bf((x1 - mean) * rstd * g[h1] + bb[h1]);
  Y[base + h2] = f2bf((x2 - mean) * rstd * g[h2] + bb[h2]);
}

// ---------------------------------------------------------------------------
// MFMA flash attention v9: T15 two-tile pipeline. Loop-carried pf (P frags)
// and va (V frags in regs); body = QK(t) -> PV(t-1) [reg-only MFMA burst]
// -> exp/pack/permlane(t) -> read V(t). The VALU/trans work of tile t now
// overlaps the matrix-pipe drain of PV(t-1) within the same wave.
// Buffer safety: all tile-(t-1) LDS reads finish before barrier(t).
// ---------------------------------------------------------------------------
__global__ __launch_bounds__(256, 3) void attn9_k(const short* __restrict__ qb,
                                                  const short* __restrict__ kb,
                                                  const short* __restrict__ vtb,
                                                  short* __restrict__ aob) {
  __shared__ short Ks[2][64 * 64];     // [sk][d] swizzled, 2 x 8 KB
  __shared__ short Vt[2][64 * 64];     // [d][sk] swizzled, 2 x 8 KB
  int tid = threadIdx.x, lane = tid & 63, w = tid >> 6;  // w 0..3
  int lm = lane & 15, lq = lane >> 4;
  int lm7 = lm & 7;
  int dd = blockIdx.x;
  int xcd = dd & 7, slot = dd >> 3;          // slot in [0,96)
  int g = xcd + 8 * (slot >> 4);             // g in [0,48)
  int qx = slot & 15;
  int b = g / NH_, n = g - b * NH_;
  int q0 = qx * 128;
  int hoff = n * HD_;

  int rb8 = (lq ^ lm7) << 3;
  int rb8x = rb8 ^ 32;

  bf16x8 qf[2][2];
#pragma unroll
  for (int qg = 0; qg < 2; ++qg) {
    const short* qrow = qb + ((size_t)(b * S_ + q0 + w * 32 + qg * 16 + lm)) * H_ + hoff;
    qf[qg][0] = *(const bf16x8*)(qrow + lq * 8);
    qf[qg][1] = *(const bf16x8*)(qrow + 32 + lq * 8);
  }

  bf16x8 onef = {0x3F80, 0x3F80, 0x3F80, 0x3F80, 0x3F80, 0x3F80, 0x3F80, 0x3F80};
  f32x4 ls[2];
  ls[0] = (f32x4){0.f, 0.f, 0.f, 0.f};
  ls[1] = (f32x4){0.f, 0.f, 0.f, 0.f};

  f32x4 o[4][2];
#pragma unroll
  for (int i = 0; i < 4; ++i)
#pragma unroll
    for (int qg = 0; qg < 2; ++qg) o[i][qg] = (f32x4){0.f, 0.f, 0.f, 0.f};

  int jl = ((lane & 7) ^ (lane >> 3)) * 8;
  int rr = w * 16 + (lane >> 3);
  const short* kgl = kb + ((size_t)(b * S_ + rr)) * H_ + hoff + jl;
  const short* vgl = vtb + ((size_t)(b * H_ + hoff + rr)) * S_ + jl;
  int lbase = w * 1024;

  // pipeline state: P fragments and V fragments of the previous tile
  bf16x8 pf[2][2];
  bf16x8 va[4][2];
  f32x4 st[4][2];

  // prologue: stage tile 0
#pragma unroll
  for (int c = 0; c < 2; ++c) {
    gload16(kgl + (size_t)(c * 8) * H_, &Ks[0][lbase + c * 512]);
    gload16(vgl + (size_t)(c * 8) * S_, &Vt[0][lbase + c * 512]);
  }
  __syncthreads();
  // prefetch tile 1
#pragma unroll
  for (int c = 0; c < 2; ++c) {
    gload16(kgl + (size_t)(64 + c * 8) * H_, &Ks[1][lbase + c * 512]);
    gload16(vgl + (size_t)(c * 8) * S_ + 64, &Vt[1][lbase + c * 512]);
  }

  // QK(0)
  __builtin_amdgcn_s_setprio(1);
#pragma unroll
  for (int ni = 0; ni < 4; ++ni) {
    int krow = (ni * 16 + lm) * 64;
    bf16x8 ka0 = *(const bf16x8*)&Ks[0][krow + rb8];
    bf16x8 ka1 = *(const bf16x8*)&Ks[0][krow + rb8x];
#pragma unroll
    for (int qg = 0; qg < 2; ++qg) {
      f32x4 z = (f32x4){0.f, 0.f, 0.f, 0.f};
      z = __builtin_amdgcn_mfma_f32_16x16x32_bf16(ka0, qf[qg][0], z, 0, 0, 0);
      st[ni][qg] = __builtin_amdgcn_mfma_f32_16x16x32_bf16(ka1, qf[qg][1], z, 0, 0, 0);
    }
  }
  __builtin_amdgcn_s_setprio(0);
  // exp(0) -> pf
#pragma unroll
  for (int qg = 0; qg < 2; ++qg) {
    unsigned pw0, pw1, pw2, pw3, pw4, pw5, pw6, pw7;
    pw0 = bfpack(fexp2(st[0][qg][0]), fexp2(st[0][qg][1]));
    pw1 = bfpack(fexp2(st[0][qg][2]), fexp2(st[0][qg][3]));
    pw2 = bfpack(fexp2(st[1][qg][0]), fexp2(st[1][qg][1]));
    pw3 = bfpack(fexp2(st[1][qg][2]), fexp2(st[1][qg][3]));
    pw4 = bfpack(fexp2(st[2][qg][0]), fexp2(st[2][qg][1]));
    pw5 = bfpack(fexp2(st[2][qg][2]), fexp2(st[2][qg][3]));
    pw6 = bfpack(fexp2(st[3][qg][0]), fexp2(st[3][qg][1]));
    pw7 = bfpack(fexp2(st[3][qg][2]), fexp2(st[3][qg][3]));
    plswap32(pw0, pw2); plswap16(pw0, pw2);
    plswap32(pw1, pw3); plswap16(pw1, pw3);
    plswap32(pw4, pw6); plswap16(pw4, pw6);
    plswap32(pw5, pw7); plswap16(pw5, pw7);
    union { u32x4 u; bf16x8 v; } c0u, c1u;
    c0u.u = (u32x4){pw0, pw1, pw2, pw3};
    c1u.u = (u32x4){pw4, pw5, pw6, pw7};
    pf[qg][0] = c0u.v;
    pf[qg][1] = c1u.v;
  }
  // read V(0) -> va
#pragma unroll
  for (int nd = 0; nd < 4; ++nd) {
    int vrow = (nd * 16 + lm) * 64;
    va[nd][0] = *(const bf16x8*)&Vt[0][vrow + rb8];
    va[nd][1] = *(const bf16x8*)&Vt[0][vrow + rb8x];
  }

  for (int t = 1; t < S_ / 64; ++t) {
    int pb = t & 1;
    __syncthreads();  // tile t ready; tile t-1 LDS reads all complete
    if (t + 1 < S_ / 64) {
      int kt1 = (t + 1) * 64;
#pragma unroll
      for (int c = 0; c < 2; ++c) {
        gload16(kgl + (size_t)(kt1 + c * 8) * H_, &Ks[pb ^ 1][lbase + c * 512]);
        gload16(vgl + (size_t)(c * 8) * S_ + kt1, &Vt[pb ^ 1][lbase + c * 512]);
      }
    }

    __builtin_amdgcn_s_setprio(1);
    // QK(t) -> st
#pragma unroll
    for (int ni = 0; ni < 4; ++ni) {
      int krow = (ni * 16 + lm) * 64;
      bf16x8 ka0 = *(const bf16x8*)&Ks[pb][krow + rb8];
      bf16x8 ka1 = *(const bf16x8*)&Ks[pb][krow + rb8x];
#pragma unroll
      for (int qg = 0; qg < 2; ++qg) {
        f32x4 z = (f32x4){0.f, 0.f, 0.f, 0.f};
        z = __builtin_amdgcn_mfma_f32_16x16x32_bf16(ka0, qf[qg][0], z, 0, 0, 0);
        st[ni][qg] = __builtin_amdgcn_mfma_f32_16x16x32_bf16(ka1, qf[qg][1], z, 0, 0, 0);
      }
    }
    // PV(t-1): register-only MFMA burst (pf, va)
#pragma unroll
    for (int qg = 0; qg < 2; ++qg) {
      ls[qg] = __builtin_amdgcn_mfma_f32_16x16x32_bf16(onef, pf[qg][0], ls[qg], 0, 0, 0);
      ls[qg] = __builtin_amdgcn_mfma_f32_16x16x32_bf16(onef, pf[qg][1], ls[qg], 0, 0, 0);
    }
#pragma unroll
    for (int nd = 0; nd < 4; ++nd)
#pragma unroll
      for (int qg = 0; qg < 2; ++qg) {
        o[nd][qg] = __builtin_amdgcn_mfma_f32_16x16x32_bf16(va[nd][0], pf[qg][0], o[nd][qg], 0, 0, 0);
        o[nd][qg] = __builtin_amdgcn_mfma_f32_16x16x32_bf16(va[nd][1], pf[qg][1], o[nd][qg], 0, 0, 0);
      }
    __builtin_amdgcn_s_setprio(0);

    // exp(t) -> pf (overlaps matrix-pipe drain of PV(t-1))
#pragma unroll
    for (int qg = 0; qg < 2; ++qg) {
      unsigned pw0, pw1, pw2, pw3, pw4, pw5, pw6, pw7;
      pw0 = bfpack(fexp2(st[0][qg][0]), fexp2(st[0][qg][1]));
      pw1 = bfpack(fexp2(st[0][qg][2]), fexp2(st[0][qg][3]));
      pw2 = bfpack(fexp2(st[1][qg][0]), fexp2(st[1][qg][1]));
      pw3 = bfpack(fexp2(st[1][qg][2]), fexp2(st[1][qg][3]));
      pw4 = bfpack(fexp2(st[2][qg][0]), fexp2(st[2][qg][1]));
      pw5 = bfpack(fexp2(st[2][qg][2]), fexp2(st[2][qg][3]));
      pw6 = bfpack(fexp2(st[3][qg][0]), fexp2(st[3][qg][1]));
      pw7 = bfpack(fexp2(st[3][qg][2]), fexp2(st[3][qg][3]));
      plswap32(pw0, pw2); plswap16(pw0, pw2);
      plswap32(pw1, pw3); plswap16(pw1, pw3);
      plswap32(pw4, pw6); plswap16(pw4, pw6);
      plswap32(pw5, pw7); plswap16(pw5, pw7);
      union { u32x4 u; bf16x8 v; } c0u, c1u;
      c0u.u = (u32x4){pw0, pw1, pw2, pw3};
      c1u.u = (u32x4){pw4, pw5, pw6, pw7};
      pf[qg][0] = c0u.v;
      pf[qg][1] = c1u.v;
    }
    // read V(t) -> va (must complete before next barrier)
#pragma unroll
    for (int nd = 0; nd < 4; ++nd) {
      int vrow = (nd * 16 + lm) * 64;
      va[nd][0] = *(const bf16x8*)&Vt[pb][vrow + rb8];
      va[nd][1] = *(const bf16x8*)&Vt[pb][vrow + rb8x];
    }
  }

  // final PV for the last tile
  __builtin_amdgcn_s_setprio(1);
#pragma unroll
  for (int qg = 0; qg < 2; ++qg) {
    ls[qg] = __builtin_amdgcn_mfma_f32_16x16x32_bf16(onef, pf[qg][0], ls[qg], 0, 0, 0);
    ls[qg] = __builtin_amdgcn_mfma_f32_16x16x32_bf16(onef, pf[qg][1], ls[qg], 0, 0, 0);
  }
#pragma unroll
  for (int nd = 0; nd < 4; ++nd)
#pragma unroll
    for (int qg = 0; qg < 2; ++qg) {
      o[nd][qg] = __builtin_amdgcn_mfma_f32_16x16x32_bf16(va[nd][0], pf[qg][0], o[nd][qg], 0, 0, 0);
      o[nd][qg] = __builtin_amdgcn_mfma_f32_16x16x32_bf16(va[nd][1], pf[qg][1], o[nd][qg], 0, 0, 0);
    }
  __builtin_amdgcn_s_setprio(0);

  // epilogue: q row = q0 + w*32 + qg*16 + lm; d = nd*16 + lq*4 + r
#pragma unroll
  for (int qg = 0; qg < 2; ++qg) {
    float inv = 1.0f / ls[qg][0];
    short* orow = aob + ((size_t)(b * S_ + q0 + w * 32 + qg * 16 + lm)) * H_ + hoff;
#pragma unroll
    for (int nd = 0; nd < 4; ++nd) {
      s16x4 pk = {f2bf(o[nd][qg][0] * inv), f2bf(o[nd][qg][1] * inv),
                  f2bf(o[nd][qg][2] * inv), f2bf(o[nd][qg][3] * inv)};
      *(s16x4*)(orow + nd * 16 + lq * 4) = pk;
    }
  }
}

// ---------------------------------------------------------------------------
// gate + masked residual + aux partials. 192 thr, x4 vectorized.
// ---------------------------------------------------------------------------
__global__ __launch_bounds__(192) void gate_out_k(const float* __restrict__ x,
                                                  const short* __restrict__ br,
                                                  const short* __restrict__ inj,
                                                  const int* __restrict__ mask,
                                                  const float* __restrict__ Wg,
                                                  const float* __restrict__ bg,
                                                  float* __restrict__ out,
                                                  float* __restrict__ paux) {
  int row = blockIdx.x;
  int b = row >> 11;
  size_t base = (size_t)row * H_;
  int h = threadIdx.x * 4;
  float4 xv = *(const float4*)(x + base + h);
  s16x4 brv = *(const s16x4*)(br + base + h);
  s16x4 inv = *(const s16x4*)(inj + base + h);
  float4 wg0 = *(const float4*)(Wg + h);
  float4 wg1 = *(const float4*)(Wg + H_ + h);
  float b0 = bf2f(brv.x), b1 = bf2f(brv.y), b2 = bf2f(brv.z), b3 = bf2f(brv.w);
  float dot = xv.x * wg0.x + xv.y * wg0.y + xv.z * wg0.z + xv.w * wg0.w
            + b0 * wg1.x + b1 * wg1.y + b2 * wg1.z + b3 * wg1.w;
  float d0 = b0 - xv.x, d1 = b1 - xv.y, d2 = b2 - xv.z, d3 = b3 - xv.w;
  float aux = d0 * d0 + d1 * d1 + d2 * d2 + d3 * d3;
  for (int off = 32; off > 0; off >>= 1) {
    dot += __shfl_down(dot, off);
    aux += __shfl_down(aux, off);
  }
  __shared__ float sd[3], sx[3], gsh[2];
  int wid = threadIdx.x >> 6, lane = threadIdx.x & 63;
  if (lane == 0) { sd[wid] = dot; sx[wid] = aux; }
  __syncthreads();
  if (threadIdx.x == 0) {
    float td = sd[0] + sd[1] + sd[2];
    float ta = sx[0] + sx[1] + sx[2];
    gsh[0] = 1.0f / (1.0f + expf(-(td + bg[0])));
    gsh[1] = ta;
  }
  __syncthreads();
  float mf = (mask[b] != 0) ? 1.0f : 0.0f;
  float gm = gsh[0] * mf;
  float v0 = bf2f(inv.x), v1 = bf2f(inv.y), v2 = bf2f(inv.z), v3 = bf2f(inv.w);
  float e0 = __expf(2.f * v0), e1 = __expf(2.f * v1), e2 = __expf(2.f * v2), e3 = __expf(2.f * v3);
  float4 ov;
  ov.x = xv.x + gm * ((e0 - 1.f) / (e0 + 1.f));
  ov.y = xv.y + gm * ((e1 - 1.f) / (e1 + 1.f));
  ov.z = xv.z + gm * ((e2 - 1.f) / (e2 + 1.f));
  ov.w = xv.w + gm * ((e3 - 1.f) / (e3 + 1.f));
  *(float4*)(out + base + h) = ov;
  if (threadIdx.x == 0) paux[row] = mf * gsh[1];
}

__global__ __launch_bounds__(256) void aux_reduce_k(const float* __restrict__ paux,
                                                    const int* __restrict__ mask,
                                                    float* __restrict__ outp) {
  float s = 0.f;
  for (int i = threadIdx.x; i < NROWS; i += 256) s += paux[i];
  for (int off = 32; off > 0; off >>= 1) s += __shfl_down(s, off);
  __shared__ float sw[4];
  int wid = threadIdx.x >> 6, lane = threadIdx.x & 63;
  if (lane == 0) sw[wid] = s;
  __syncthreads();
  if (threadIdx.x == 0) {
    float t = sw[0] + sw[1] + sw[2] + sw[3];
    int nm = (mask[0] != 0) + (mask[1] != 0) + (mask[2] != 0) + (mask[3] != 0);
    if (nm < 1) nm = 1;
    outp[0] = t / ((float)nm * (float)(S_ * H_));
  }
}

// ---------------------------------------------------------------------------
extern "C" void kernel_launch(void* const* d_in, const int* in_sizes, int n_in,
                              void* d_out, int out_size, void* d_ws, size_t ws_size,
                              hipStream_t stream) {
  const float* x     = (const float*)d_in[0];
  const float* prev  = (const float*)d_in[1];
  const int*   mask  = (const int*)d_in[2];
  const float* dw_w  = (const float*)d_in[3];
  const float* dw_b  = (const float*)d_in[4];
  const float* pw_w  = (const float*)d_in[5];
  const float* pw_b  = (const float*)d_in[6];
  const float* cn_g  = (const float*)d_in[7];
  const float* cn_b  = (const float*)d_in[8];
  const float* Wq    = (const float*)d_in[9];
  const float* bq    = (const float*)d_in[10];
  const float* Wk    = (const float*)d_in[11];
  const float* bk    = (const float*)d_in[12];
  const float* Wv    = (const float*)d_in[13];
  const float* bv    = (const float*)d_in[14];
  const float* Wo    = (const float*)d_in[15];
  const float* bo    = (const float*)d_in[16];
  const float* pn_g  = (const float*)d_in[17];
  const float* pn_b  = (const float*)d_in[18];
  const float* Wpost = (const float*)d_in[19];
  const float* bpost = (const float*)d_in[20];
  const float* Wg    = (const float*)d_in[21];
  const float* bg    = (const float*)d_in[22];
  float* out = (float*)d_out;

  short* B0 = (short*)d_ws;     // xb
  short* B1 = B0 + BSH;         // dwo -> qb
  short* B2 = B1 + BSH;         // gelu-out -> aob
  short* B3 = B2 + BSH;         // bridged (until gate)
  short* B4 = B3 + BSH;         // kb -> ao_proj -> pn
  short* B5 = B4 + BSH;         // vtb -> injb
  short* WW = B5 + BSH;         // 6 bf16 weights [pw,q,k,v,o,post]
  float* paux = (float*)(WW + 6 * WSZ);

  const float C1 = 0.1803368802f;  // 0.125 * log2(e), folded into Wq/bq

  GemmJob jq = {B0, WW + WSZ,     bq, B1, 0, 0, C1};
  GemmJob jk = {B3, WW + 2 * WSZ, bk, B4, 0, 0, 1.0f};
  GemmJob jv = {B3, WW + 3 * WSZ, bv, B5, 0, 1, 1.0f};

  cvt6_k<<<6 * WSZ / 1024, 256, 0, stream>>>(pw_w, Wq, Wk, Wv, Wo, Wpost, WW);
  cvt_x_k<<<BSH / 1024, 256, 0, stream>>>(x, B0);
  dwconv_k<<<NROWS, 192, 0, stream>>>(prev, dw_w, dw_b, B1);
  gemm_n64<<<768, 256, 0, stream>>>(B1, WW, pw_b, B2, 1);                  // pw + GELU
  ln_bf<<<NROWS, 256, 0, stream>>>(B2, B3, cn_g, cn_b);                    // bridged
  gemm_bf2<<<1152, 256, 0, stream>>>(jq, jk, jv);                          // Q,K,V grouped
  attn9_k<<<768, 256, 0, stream>>>(B1, B4, B5, B2);                        // -> aob
  gemm_n64<<<768, 256, 0, stream>>>(B2, WW + 4 * WSZ, bo, B4, 0);          // o-proj
  ln_bf<<<NROWS, 256, 0, stream>>>(B4, B4, pn_g, pn_b);                    // pn
  gemm_n64<<<768, 256, 0, stream>>>(B4, WW + 5 * WSZ, bpost, B5, 0);       // post
  gate_out_k<<<NROWS, 192, 0, stream>>>(x, B3, B5, mask, Wg, bg, out, paux);
  aux_reduce_k<<<1, 256, 0, stream>>>(paux, mask, out + BSH);
}